// Round 5
// baseline (20410.423 us; speedup 1.0000x reference)
//
#include <hip/hip_runtime.h>

// LSTM 2-layer, S=512 B=64 IN=H=1024, fp32 I/O, fp16 MFMA compute.
// R5 = R4 with two fixes:
//   (1) wv>=2 layer0 weight column = wcol (was wcol+1024: read next row's
//       x-weights -> absmax 5e-2).
//   (2) explicit s_waitcnt vmcnt(0) after inline-asm h stores (compiler can't
//       see asm VMEM ops, so __syncthreads alone doesn't guarantee drain).
// Design: single-aggregator epoch barrier + layer pipelining (round k =
// layer0 step k  AND layer1 step k-1; 514 global sync rounds).

#define SEQ   512
#define BATCH 64
#define HID   1024
#define NG    4096           // 4*HID
#define KCAT  2048           // IN + HID
#define EPOCH_IDX 8192       // flags[] index of the epoch line

typedef __attribute__((ext_vector_type(8))) _Float16 f16x8;
typedef __attribute__((ext_vector_type(4))) _Float16 f16x4;
typedef __attribute__((ext_vector_type(4))) float    f32x4;

__device__ __forceinline__ float sigm_f(float x){ return 1.f/(1.f + __expf(-x)); }
__device__ __forceinline__ float tanh_f(float x){
    float e = __expf(-2.f*fabsf(x));
    float r = (1.f - e)/(1.f + e);
    return copysignf(r, x);
}

// write-through/bypass 8B store (visible at LLC once vmcnt==0)
__device__ __forceinline__ void store_h8(_Float16* p, f16x4 v){
    asm volatile("global_store_dwordx2 %0, %1, off sc0 sc1" :: "v"(p), "v"(v) : "memory");
}
__device__ __forceinline__ void drain_vmem(){
    asm volatile("s_waitcnt vmcnt(0)" ::: "memory");
}

// ---------------- prep kernels ----------------

__global__ void prep_w_kernel(const float* __restrict__ Wx, const float* __restrict__ Wh,
                              const float* __restrict__ bx, const float* __restrict__ bh,
                              _Float16* __restrict__ Wr, float* __restrict__ br){
    int p = blockIdx.x;            // 0..4095 reordered row
    int j = p >> 2, g = p & 3;
    int r = g*1024 + j;            // original row in Wx/Wh
    int k = threadIdx.x * 8;       // 0..2040
    const float* s = (k < 1024) ? (Wx + (size_t)r*1024 + k)
                                : (Wh + (size_t)r*1024 + (k - 1024));
    float4 v0 = *reinterpret_cast<const float4*>(s);
    float4 v1 = *reinterpret_cast<const float4*>(s + 4);
    f16x8 o;
    o[0]=(_Float16)v0.x; o[1]=(_Float16)v0.y; o[2]=(_Float16)v0.z; o[3]=(_Float16)v0.w;
    o[4]=(_Float16)v1.x; o[5]=(_Float16)v1.y; o[6]=(_Float16)v1.z; o[7]=(_Float16)v1.w;
    *reinterpret_cast<f16x8*>(Wr + (size_t)p*KCAT + k) = o;
    if (threadIdx.x == 0) br[p] = bx[r] + bh[r];
}

__global__ void init_misc_kernel(int* flags, _Float16* hz){
    int i = blockIdx.x*256 + threadIdx.x;            // 16384 threads
    flags[i] = 0;                                    // 64 KB flag area (incl epoch)
    size_t j = (size_t)i * 4;
    if (j < (size_t)BATCH*HID){
        f16x4 z; z[0]=(_Float16)0.f; z[1]=(_Float16)0.f; z[2]=(_Float16)0.f; z[3]=(_Float16)0.f;
        *reinterpret_cast<f16x4*>(hz + j) = z;
    }
}

// ---------------- barrier helpers (no fences, no poll-storm) ----------------

__device__ __forceinline__ void wait_epoch(const int* flags, int k){
    for(;;){
        int e = __hip_atomic_load(&flags[EPOCH_IDX], __ATOMIC_RELAXED, __HIP_MEMORY_SCOPE_AGENT);
        if (e >= k) break;
        __builtin_amdgcn_s_sleep(1);
    }
    asm volatile("" ::: "memory");
}

// wg0/wave2 only: poll all 256 per-wg flags, then publish epoch=k
__device__ __forceinline__ void aggregate_publish(int* flags, int k, int lane){
    const int b = lane*4;
    for(;;){
        int a0 = __hip_atomic_load(&flags[(b+0)*32], __ATOMIC_RELAXED, __HIP_MEMORY_SCOPE_AGENT);
        int a1 = __hip_atomic_load(&flags[(b+1)*32], __ATOMIC_RELAXED, __HIP_MEMORY_SCOPE_AGENT);
        int a2 = __hip_atomic_load(&flags[(b+2)*32], __ATOMIC_RELAXED, __HIP_MEMORY_SCOPE_AGENT);
        int a3 = __hip_atomic_load(&flags[(b+3)*32], __ATOMIC_RELAXED, __HIP_MEMORY_SCOPE_AGENT);
        bool ok = (a0>=k) && (a1>=k) && (a2>=k) && (a3>=k);
        if (__all(ok)) break;
        __builtin_amdgcn_s_sleep(1);
    }
    asm volatile("" ::: "memory");
    if (lane == 0)
        __hip_atomic_store(&flags[EPOCH_IDX], k, __ATOMIC_RELAXED, __HIP_MEMORY_SCOPE_AGENT);
}

// ---------------- GEMM quarter helpers ----------------
// A rows r, r+16, r+32, r+48 ; this wave's k-offset pre-applied by caller.

__device__ __forceinline__ f32x4 mfma16(f16x8 a, f16x8 b, f32x4 c){
    return __builtin_amdgcn_mfma_f32_16x16x32_f16(a, b, c, 0, 0, 0);
}

__device__ __forceinline__ void gemm_q_f16(const _Float16* A, const _Float16* Wp, f32x4* acc){
    #pragma unroll 4
    for (int kk = 0; kk < 16; ++kk){
        f16x8 b  = *reinterpret_cast<const f16x8*>(Wp + kk*32);
        f16x8 a0 = *reinterpret_cast<const f16x8*>(A + kk*32);
        f16x8 a1 = *reinterpret_cast<const f16x8*>(A + kk*32 + 16*1024);
        f16x8 a2 = *reinterpret_cast<const f16x8*>(A + kk*32 + 32*1024);
        f16x8 a3 = *reinterpret_cast<const f16x8*>(A + kk*32 + 48*1024);
        acc[0] = mfma16(a0, b, acc[0]);
        acc[1] = mfma16(a1, b, acc[1]);
        acc[2] = mfma16(a2, b, acc[2]);
        acc[3] = mfma16(a3, b, acc[3]);
    }
}

__device__ __forceinline__ void gemm_q_f32(const float* A, const _Float16* Wp, f32x4* acc){
    #pragma unroll 2
    for (int kk = 0; kk < 16; ++kk){
        f16x8 b = *reinterpret_cast<const f16x8*>(Wp + kk*32);
        f16x8 a[4];
        #pragma unroll
        for (int m = 0; m < 4; ++m){
            float4 u0 = *reinterpret_cast<const float4*>(A + kk*32 + (size_t)m*16*1024);
            float4 u1 = *reinterpret_cast<const float4*>(A + kk*32 + (size_t)m*16*1024 + 4);
            f16x8 v;
            v[0]=(_Float16)u0.x; v[1]=(_Float16)u0.y; v[2]=(_Float16)u0.z; v[3]=(_Float16)u0.w;
            v[4]=(_Float16)u1.x; v[5]=(_Float16)u1.y; v[6]=(_Float16)u1.z; v[7]=(_Float16)u1.w;
            a[m] = v;
        }
        acc[0] = mfma16(a[0], b, acc[0]);
        acc[1] = mfma16(a[1], b, acc[1]);
        acc[2] = mfma16(a[2], b, acc[2]);
        acc[3] = mfma16(a[3], b, acc[3]);
    }
}

// ---------------- persistent LSTM kernel ----------------

__global__ __launch_bounds__(256, 1)
void lstm_persist(const _Float16* __restrict__ Wr0, const _Float16* __restrict__ Wr1,
                  const float* __restrict__ br0, const float* __restrict__ br1,
                  const float* __restrict__ x, const _Float16* __restrict__ hz,
                  _Float16* h0ring, _Float16* h1ring, float* out, int* flags){
    const int tid  = threadIdx.x;
    const int wg   = blockIdx.x;          // 0..255
    const int wv   = tid >> 6;            // wave 0..3
    const int lane = tid & 63;
    const int r    = lane & 15;           // MFMA row-in-tile (batch row base / gate col)
    const int q    = lane >> 4;           // k-subgroup 0..3
    const int p0   = wg * 16;             // gate-row base (16 rows = 4 h-cols)

    __shared__ float accL[2][4][64][17];  // [layer][wave][batch][gate16], padded

    f32x4 cst = {0.f,0.f,0.f,0.f};        // wave0: c(layer0); wave1: c(layer1)
    f32x4 ho_keep = {0.f,0.f,0.f,0.f};    // wave1: out[511] deferred

    const int kofs = (wv & 1)*512 + q*8;  // within-half k offset (elements)

    for (int k = 0; k <= SEQ; ++k){
        f32x4 acc0[4], acc1[4];
        #pragma unroll
        for (int m = 0; m < 4; ++m){
            acc0[m].x=0;acc0[m].y=0;acc0[m].z=0;acc0[m].w=0;
            acc1[m].x=0;acc1[m].y=0;acc1[m].z=0;acc1[m].w=0;
        }
        const int wcol = wv*512 + q*8;    // weight k-column base for this wave

        if (wv < 2){
            // dep-free x-GEMM (layer0) first, then wait, then hseq0-GEMM (layer1)
            if (k < SEQ)
                gemm_q_f32(x + (size_t)k*BATCH*1024 + (size_t)r*1024 + kofs,
                           Wr0 + (size_t)(p0 + r)*KCAT + wcol, acc0);
            if (k > 0){
                wait_epoch(flags, k);
                gemm_q_f16(h0ring + (size_t)(k-1)*BATCH*HID + (size_t)r*HID + kofs,
                           Wr1 + (size_t)(p0 + r)*KCAT + wcol, acc1);
            }
        } else {
            if (k > 0){
                if (wg == 0 && wv == 2) aggregate_publish(flags, k, lane);
                else                    wait_epoch(flags, k);
            }
            if (k < SEQ){
                const _Float16* A0 = (k == 0) ? (hz + (size_t)r*HID + kofs)
                                              : (h0ring + (size_t)(k-1)*BATCH*HID + (size_t)r*HID + kofs);
                gemm_q_f16(A0, Wr0 + (size_t)(p0 + r)*KCAT + wcol, acc0);   // FIXED: was wcol+1024
            }
            if (k >= 1){
                const _Float16* A1 = (k == 1) ? (hz + (size_t)r*HID + kofs)
                                              : (h1ring + (size_t)(k-2)*BATCH*HID + (size_t)r*HID + kofs);
                gemm_q_f16(A1, Wr1 + (size_t)(p0 + r)*KCAT + wcol, acc1);
            }
        }

        __syncthreads();   // #1: prev round's elementwise LDS reads complete

        #pragma unroll
        for (int mt = 0; mt < 4; ++mt){
            #pragma unroll
            for (int j = 0; j < 4; ++j){
                accL[0][wv][mt*16 + q*4 + j][r] = acc0[mt][j];
                accL[1][wv][mt*16 + q*4 + j][r] = acc1[mt][j];
            }
        }
        __syncthreads();   // #2: partials visible

        if (wv == 0 && k < SEQ){
            // elementwise layer0: lane = batch row, 4 h-cols
            f32x4 zz[4];
            #pragma unroll
            for (int jj = 0; jj < 4; ++jj) zz[jj] = *reinterpret_cast<const f32x4*>(&br0[p0 + jj*4]);
            #pragma unroll
            for (int w2 = 0; w2 < 4; ++w2)
                #pragma unroll
                for (int jj = 0; jj < 4; ++jj){
                    f32x4 a = *reinterpret_cast<const f32x4*>(&accL[0][w2][lane][jj*4]);
                    zz[jj].x += a.x; zz[jj].y += a.y; zz[jj].z += a.z; zz[jj].w += a.w;
                }
            f16x4 hv;
            #pragma unroll
            for (int jl = 0; jl < 4; ++jl){
                float ig = sigm_f(zz[jl].x), fg = sigm_f(zz[jl].y);
                float gg = tanh_f(zz[jl].z), og = sigm_f(zz[jl].w);
                float c = fg*cst[jl] + ig*gg;  cst[jl] = c;
                hv[jl] = (_Float16)(og * tanh_f(c));
            }
            store_h8(h0ring + ((size_t)k*BATCH + lane)*HID + wg*4, hv);
            drain_vmem();                               // h at LLC before barrier
        }
        if (wv == 1 && k >= 1){
            const int t1 = k - 1;
            f32x4 zz[4];
            #pragma unroll
            for (int jj = 0; jj < 4; ++jj) zz[jj] = *reinterpret_cast<const f32x4*>(&br1[p0 + jj*4]);
            #pragma unroll
            for (int w2 = 0; w2 < 4; ++w2)
                #pragma unroll
                for (int jj = 0; jj < 4; ++jj){
                    f32x4 a = *reinterpret_cast<const f32x4*>(&accL[1][w2][lane][jj*4]);
                    zz[jj].x += a.x; zz[jj].y += a.y; zz[jj].z += a.z; zz[jj].w += a.w;
                }
            f16x4 hv; f32x4 ho;
            #pragma unroll
            for (int jl = 0; jl < 4; ++jl){
                float ig = sigm_f(zz[jl].x), fg = sigm_f(zz[jl].y);
                float gg = tanh_f(zz[jl].z), og = sigm_f(zz[jl].w);
                float c = fg*cst[jl] + ig*gg;  cst[jl] = c;
                float h = og * tanh_f(c);
                hv[jl] = (_Float16)h;  ho[jl] = h;
            }
            if (k < SEQ) store_h8(h1ring + ((size_t)t1*BATCH + lane)*HID + wg*4, hv);
            if (t1 < SEQ-1) *reinterpret_cast<f32x4*>(out + ((size_t)t1*BATCH + lane)*HID + wg*4) = ho;
            else            ho_keep = ho;  // defer: aliases hseq0[511] region when h0ring==d_out
            drain_vmem();                               // h1 (+out) drained before barrier
        }

        __syncthreads();   // #3: all waves' stores drained -> flag release is safe
        if (tid == 0)
            __hip_atomic_store(&flags[wg*32], k + 1, __ATOMIC_RELAXED, __HIP_MEMORY_SCOPE_AGENT);
    }

    // epilogue: ensure every wg finished round 512's reads, then store out[511]
    if (wg == 0 && wv == 2) aggregate_publish(flags, SEQ + 1, lane);
    if (wv == 1){
        wait_epoch(flags, SEQ + 1);
        *reinterpret_cast<f32x4*>(out + ((size_t)(SEQ-1)*BATCH + lane)*HID + wg*4) = ho_keep;
    }
}

// ---------------- host launcher ----------------

extern "C" void kernel_launch(void* const* d_in, const int* in_sizes, int n_in,
                              void* d_out, int out_size, void* d_ws, size_t ws_size,
                              hipStream_t stream){
    const float* x   = (const float*)d_in[0];
    const float* Wx0 = (const float*)d_in[1];
    const float* bx0 = (const float*)d_in[2];
    const float* Wh0 = (const float*)d_in[3];
    const float* bh0 = (const float*)d_in[4];
    const float* Wx1 = (const float*)d_in[5];
    const float* bx1 = (const float*)d_in[6];
    const float* Wh1 = (const float*)d_in[7];
    const float* bh1 = (const float*)d_in[8];
    float* out = (float*)d_out;
    char* ws = (char*)d_ws;

    size_t o = 0;
    _Float16* Wr0 = (_Float16*)(ws + o); o += (size_t)NG*KCAT*2;          // 16 MB
    _Float16* Wr1 = (_Float16*)(ws + o); o += (size_t)NG*KCAT*2;          // 16 MB
    float* br0 = (float*)(ws + o); o += 16384;
    float* br1 = (float*)(ws + o); o += 16384;
    _Float16* h1ring = (_Float16*)(ws + o); o += (size_t)SEQ*BATCH*HID*2; // 64 MB
    _Float16* hz     = (_Float16*)(ws + o); o += (size_t)BATCH*HID*2;     // 128 KB
    int* flags = (int*)(ws + o); o += 65536;
    // h0ring: prefer ws; else alias d_out upper half (64..128 MiB).
    //   alias safety: h0 slot k bytes == out[256+k/2] bytes; out[256+s] written
    //   at round 257+s, h0 slot 2s/2s+1 written at rounds 2s,2s+1 and last read
    //   at round 2s+2 <= 256+s (epoch-ordered) for s<255; only out[511] vs
    //   h0[511] collide in round 512 -> out[511] deferred past epoch 513.
    _Float16* h0ring;
    if (ws_size >= o + (size_t)SEQ*BATCH*HID*2) h0ring = (_Float16*)(ws + o);
    else h0ring = (_Float16*)((char*)d_out + (size_t)64*1024*1024);

    prep_w_kernel<<<NG, 256, 0, stream>>>(Wx0, Wh0, bx0, bh0, Wr0, br0);
    prep_w_kernel<<<NG, 256, 0, stream>>>(Wx1, Wh1, bx1, bh1, Wr1, br1);
    init_misc_kernel<<<64, 256, 0, stream>>>(flags, hz);
    lstm_persist<<<256, 256, 0, stream>>>(Wr0, Wr1, br0, br1, x, hz, h0ring, h1ring, out, flags);
}

// Round 6
// 10894.167 us; speedup vs baseline: 1.8735x; 1.8735x over previous
//
#include <hip/hip_runtime.h>

// LSTM 2-layer, S=512 B=64 IN=H=1024, fp32 I/O, fp16 MFMA compute.
// R6 = R5 + poll-contention fixes:
//   (1) epoch replicated on 8 lines; ONLY wave3 of each wg polls globally
//       (wg&7 replica), mirrors into LDS; waves 0-2 spin on LDS.
//   (2) x pre-converted to f16 (xbf) when ws allows; else f32 path.
//   (3) bias hoisted out of round loop.
// Structure: persistent 256 wg x 256 thr; round k = layer0 step k + layer1
// step k-1 (514 rounds); h via sc0|sc1 stores into full-length rings;
// no fences anywhere in the loop (no wbl2/inv).

#define SEQ   512
#define BATCH 64
#define HID   1024
#define NG    4096           // 4*HID
#define KCAT  2048           // IN + HID
#define EPOCH_IDX 8192       // flags[] base index of the 8 epoch replica lines

typedef __attribute__((ext_vector_type(8))) _Float16 f16x8;
typedef __attribute__((ext_vector_type(4))) _Float16 f16x4;
typedef __attribute__((ext_vector_type(4))) float    f32x4;

__device__ __forceinline__ float sigm_f(float x){ return 1.f/(1.f + __expf(-x)); }
__device__ __forceinline__ float tanh_f(float x){
    float e = __expf(-2.f*fabsf(x));
    float r = (1.f - e)/(1.f + e);
    return copysignf(r, x);
}

__device__ __forceinline__ void store_h8(_Float16* p, f16x4 v){
    asm volatile("global_store_dwordx2 %0, %1, off sc0 sc1" :: "v"(p), "v"(v) : "memory");
}
__device__ __forceinline__ void drain_vmem(){
    asm volatile("s_waitcnt vmcnt(0)" ::: "memory");
}

// ---------------- prep kernels ----------------

__global__ void prep_w_kernel(const float* __restrict__ Wx, const float* __restrict__ Wh,
                              const float* __restrict__ bx, const float* __restrict__ bh,
                              _Float16* __restrict__ Wr, float* __restrict__ br){
    int p = blockIdx.x;            // 0..4095 reordered row
    int j = p >> 2, g = p & 3;
    int r = g*1024 + j;            // original row in Wx/Wh
    int k = threadIdx.x * 8;       // 0..2040
    const float* s = (k < 1024) ? (Wx + (size_t)r*1024 + k)
                                : (Wh + (size_t)r*1024 + (k - 1024));
    float4 v0 = *reinterpret_cast<const float4*>(s);
    float4 v1 = *reinterpret_cast<const float4*>(s + 4);
    f16x8 o;
    o[0]=(_Float16)v0.x; o[1]=(_Float16)v0.y; o[2]=(_Float16)v0.z; o[3]=(_Float16)v0.w;
    o[4]=(_Float16)v1.x; o[5]=(_Float16)v1.y; o[6]=(_Float16)v1.z; o[7]=(_Float16)v1.w;
    *reinterpret_cast<f16x8*>(Wr + (size_t)p*KCAT + k) = o;
    if (threadIdx.x == 0) br[p] = bx[r] + bh[r];
}

__global__ void prep_x_kernel(const float* __restrict__ x, _Float16* xo){
    size_t i = ((size_t)blockIdx.x*256 + threadIdx.x) * 8;
    float4 v0 = *reinterpret_cast<const float4*>(x + i);
    float4 v1 = *reinterpret_cast<const float4*>(x + i + 4);
    f16x8 o;
    o[0]=(_Float16)v0.x; o[1]=(_Float16)v0.y; o[2]=(_Float16)v0.z; o[3]=(_Float16)v0.w;
    o[4]=(_Float16)v1.x; o[5]=(_Float16)v1.y; o[6]=(_Float16)v1.z; o[7]=(_Float16)v1.w;
    *reinterpret_cast<f16x8*>(xo + i) = o;
}

__global__ void init_misc_kernel(int* flags, _Float16* hz){
    int i = blockIdx.x*256 + threadIdx.x;            // 16384 threads
    flags[i] = 0;                                    // flags + epoch replicas
    size_t j = (size_t)i * 4;
    if (j < (size_t)BATCH*HID){
        f16x4 z; z[0]=(_Float16)0.f; z[1]=(_Float16)0.f; z[2]=(_Float16)0.f; z[3]=(_Float16)0.f;
        *reinterpret_cast<f16x4*>(hz + j) = z;
    }
}

// ---------------- sync helpers (no fences) ----------------

__device__ __forceinline__ void wait_epoch_g(const int* flags, int k, int rep){
    for(;;){
        int e = __hip_atomic_load(&flags[EPOCH_IDX + rep*32], __ATOMIC_RELAXED, __HIP_MEMORY_SCOPE_AGENT);
        if (e >= k) break;
        __builtin_amdgcn_s_sleep(2);
    }
    asm volatile("" ::: "memory");
}

// wg0/wave3 only: poll all 256 per-wg flags, then publish epoch to 8 replicas
__device__ __forceinline__ void aggregate_publish(int* flags, int k, int lane){
    const int b = lane*4;
    for(;;){
        int a0 = __hip_atomic_load(&flags[(b+0)*32], __ATOMIC_RELAXED, __HIP_MEMORY_SCOPE_AGENT);
        int a1 = __hip_atomic_load(&flags[(b+1)*32], __ATOMIC_RELAXED, __HIP_MEMORY_SCOPE_AGENT);
        int a2 = __hip_atomic_load(&flags[(b+2)*32], __ATOMIC_RELAXED, __HIP_MEMORY_SCOPE_AGENT);
        int a3 = __hip_atomic_load(&flags[(b+3)*32], __ATOMIC_RELAXED, __HIP_MEMORY_SCOPE_AGENT);
        bool ok = (a0>=k) && (a1>=k) && (a2>=k) && (a3>=k);
        if (__all(ok)) break;
        __builtin_amdgcn_s_sleep(1);
    }
    asm volatile("" ::: "memory");
    if (lane < 8)
        __hip_atomic_store(&flags[EPOCH_IDX + lane*32], k, __ATOMIC_RELAXED, __HIP_MEMORY_SCOPE_AGENT);
}

__device__ __forceinline__ void lds_publish(int* e, int k){
    __hip_atomic_store(e, k, __ATOMIC_RELAXED, __HIP_MEMORY_SCOPE_WORKGROUP);
}
__device__ __forceinline__ void lds_wait(int* e, int k){
    while (__hip_atomic_load(e, __ATOMIC_RELAXED, __HIP_MEMORY_SCOPE_WORKGROUP) < k)
        __builtin_amdgcn_s_sleep(1);
    asm volatile("" ::: "memory");
}

// ---------------- GEMM quarter helpers ----------------

__device__ __forceinline__ f32x4 mfma16(f16x8 a, f16x8 b, f32x4 c){
    return __builtin_amdgcn_mfma_f32_16x16x32_f16(a, b, c, 0, 0, 0);
}

__device__ __forceinline__ void gemm_q_f16(const _Float16* A, const _Float16* Wp, f32x4* acc){
    #pragma unroll 4
    for (int kk = 0; kk < 16; ++kk){
        f16x8 b  = *reinterpret_cast<const f16x8*>(Wp + kk*32);
        f16x8 a0 = *reinterpret_cast<const f16x8*>(A + kk*32);
        f16x8 a1 = *reinterpret_cast<const f16x8*>(A + kk*32 + 16*1024);
        f16x8 a2 = *reinterpret_cast<const f16x8*>(A + kk*32 + 32*1024);
        f16x8 a3 = *reinterpret_cast<const f16x8*>(A + kk*32 + 48*1024);
        acc[0] = mfma16(a0, b, acc[0]);
        acc[1] = mfma16(a1, b, acc[1]);
        acc[2] = mfma16(a2, b, acc[2]);
        acc[3] = mfma16(a3, b, acc[3]);
    }
}

__device__ __forceinline__ void gemm_q_f32(const float* A, const _Float16* Wp, f32x4* acc){
    #pragma unroll 2
    for (int kk = 0; kk < 16; ++kk){
        f16x8 b = *reinterpret_cast<const f16x8*>(Wp + kk*32);
        f16x8 a[4];
        #pragma unroll
        for (int m = 0; m < 4; ++m){
            float4 u0 = *reinterpret_cast<const float4*>(A + kk*32 + (size_t)m*16*1024);
            float4 u1 = *reinterpret_cast<const float4*>(A + kk*32 + (size_t)m*16*1024 + 4);
            f16x8 v;
            v[0]=(_Float16)u0.x; v[1]=(_Float16)u0.y; v[2]=(_Float16)u0.z; v[3]=(_Float16)u0.w;
            v[4]=(_Float16)u1.x; v[5]=(_Float16)u1.y; v[6]=(_Float16)u1.z; v[7]=(_Float16)u1.w;
            a[m] = v;
        }
        acc[0] = mfma16(a[0], b, acc[0]);
        acc[1] = mfma16(a[1], b, acc[1]);
        acc[2] = mfma16(a[2], b, acc[2]);
        acc[3] = mfma16(a[3], b, acc[3]);
    }
}

// ---------------- persistent LSTM kernel ----------------

__global__ __launch_bounds__(256, 1)
void lstm_persist(const _Float16* __restrict__ Wr0, const _Float16* __restrict__ Wr1,
                  const float* __restrict__ br0, const float* __restrict__ br1,
                  const _Float16* __restrict__ xbf, const float* __restrict__ xf32,
                  int use_xf16, const _Float16* __restrict__ hz,
                  _Float16* h0ring, _Float16* h1ring, float* out, int* flags){
    const int tid  = threadIdx.x;
    const int wg   = blockIdx.x;          // 0..255
    const int wv   = tid >> 6;            // wave 0..3
    const int lane = tid & 63;
    const int r    = lane & 15;
    const int q    = lane >> 4;
    const int p0   = wg * 16;             // gate-row base (16 rows = 4 h-cols)
    const int rep  = wg & 7;

    __shared__ float accL[2][4][64][17];  // [layer][wave][batch][gate16], padded
    __shared__ int   lds_epoch;

    if (tid == 0) lds_epoch = 0;
    __syncthreads();

    f32x4 cst = {0.f,0.f,0.f,0.f};        // wave0: c(layer0); wave1: c(layer1)
    f32x4 ho_keep = {0.f,0.f,0.f,0.f};    // wave1: out[511] deferred
    f32x4 bias[4];                        // wave0: br0, wave1: br1 (others unused)
    {
        const float* bsrc = (wv == 0) ? br0 : br1;
        #pragma unroll
        for (int jj = 0; jj < 4; ++jj)
            bias[jj] = *reinterpret_cast<const f32x4*>(&bsrc[p0 + jj*4]);
    }

    const int kofs = (wv & 1)*512 + q*8;  // A k-offset within 1024-half
    const int wcol = wv*512 + q*8;        // weight k-column base

    for (int k = 0; k <= SEQ; ++k){
        f32x4 acc0[4], acc1[4];
        #pragma unroll
        for (int m = 0; m < 4; ++m){
            acc0[m].x=0;acc0[m].y=0;acc0[m].z=0;acc0[m].w=0;
            acc1[m].x=0;acc1[m].y=0;acc1[m].z=0;acc1[m].w=0;
        }

        if (wv < 2){
            // dep-free x-GEMM first, then LDS-epoch wait, then layer1 h0-GEMM
            if (k < SEQ){
                if (use_xf16)
                    gemm_q_f16(xbf + (size_t)k*BATCH*HID + (size_t)r*HID + kofs,
                               Wr0 + (size_t)(p0 + r)*KCAT + wcol, acc0);
                else
                    gemm_q_f32(xf32 + (size_t)k*BATCH*1024 + (size_t)r*1024 + kofs,
                               Wr0 + (size_t)(p0 + r)*KCAT + wcol, acc0);
            }
            if (k > 0){
                lds_wait(&lds_epoch, k);
                gemm_q_f16(h0ring + (size_t)(k-1)*BATCH*HID + (size_t)r*HID + kofs,
                           Wr1 + (size_t)(p0 + r)*KCAT + wcol, acc1);
            }
        } else {
            if (k > 0){
                if (wv == 3){
                    if (wg == 0) aggregate_publish(flags, k, lane);
                    else         wait_epoch_g(flags, k, rep);
                    lds_publish(&lds_epoch, k);
                } else {
                    lds_wait(&lds_epoch, k);
                }
            }
            if (k < SEQ){
                const _Float16* A0 = (k == 0) ? (hz + (size_t)r*HID + kofs)
                                              : (h0ring + (size_t)(k-1)*BATCH*HID + (size_t)r*HID + kofs);
                gemm_q_f16(A0, Wr0 + (size_t)(p0 + r)*KCAT + wcol, acc0);
            }
            if (k >= 1){
                const _Float16* A1 = (k == 1) ? (hz + (size_t)r*HID + kofs)
                                              : (h1ring + (size_t)(k-2)*BATCH*HID + (size_t)r*HID + kofs);
                gemm_q_f16(A1, Wr1 + (size_t)(p0 + r)*KCAT + wcol, acc1);
            }
        }

        __syncthreads();   // #1: prev round's elementwise LDS reads complete

        #pragma unroll
        for (int mt = 0; mt < 4; ++mt){
            #pragma unroll
            for (int j = 0; j < 4; ++j){
                accL[0][wv][mt*16 + q*4 + j][r] = acc0[mt][j];
                accL[1][wv][mt*16 + q*4 + j][r] = acc1[mt][j];
            }
        }
        __syncthreads();   // #2: partials visible

        if (wv == 0 && k < SEQ){
            f32x4 zz[4];
            #pragma unroll
            for (int jj = 0; jj < 4; ++jj) zz[jj] = bias[jj];
            #pragma unroll
            for (int w2 = 0; w2 < 4; ++w2)
                #pragma unroll
                for (int jj = 0; jj < 4; ++jj){
                    f32x4 a = *reinterpret_cast<const f32x4*>(&accL[0][w2][lane][jj*4]);
                    zz[jj].x += a.x; zz[jj].y += a.y; zz[jj].z += a.z; zz[jj].w += a.w;
                }
            f16x4 hv;
            #pragma unroll
            for (int jl = 0; jl < 4; ++jl){
                float ig = sigm_f(zz[jl].x), fg = sigm_f(zz[jl].y);
                float gg = tanh_f(zz[jl].z), og = sigm_f(zz[jl].w);
                float c = fg*cst[jl] + ig*gg;  cst[jl] = c;
                hv[jl] = (_Float16)(og * tanh_f(c));
            }
            store_h8(h0ring + ((size_t)k*BATCH + lane)*HID + wg*4, hv);
            drain_vmem();
        }
        if (wv == 1 && k >= 1){
            const int t1 = k - 1;
            f32x4 zz[4];
            #pragma unroll
            for (int jj = 0; jj < 4; ++jj) zz[jj] = bias[jj];
            #pragma unroll
            for (int w2 = 0; w2 < 4; ++w2)
                #pragma unroll
                for (int jj = 0; jj < 4; ++jj){
                    f32x4 a = *reinterpret_cast<const f32x4*>(&accL[1][w2][lane][jj*4]);
                    zz[jj].x += a.x; zz[jj].y += a.y; zz[jj].z += a.z; zz[jj].w += a.w;
                }
            f16x4 hv; f32x4 ho;
            #pragma unroll
            for (int jl = 0; jl < 4; ++jl){
                float ig = sigm_f(zz[jl].x), fg = sigm_f(zz[jl].y);
                float gg = tanh_f(zz[jl].z), og = sigm_f(zz[jl].w);
                float c = fg*cst[jl] + ig*gg;  cst[jl] = c;
                float h = og * tanh_f(c);
                hv[jl] = (_Float16)h;  ho[jl] = h;
            }
            if (k < SEQ) store_h8(h1ring + ((size_t)t1*BATCH + lane)*HID + wg*4, hv);
            if (t1 < SEQ-1) *reinterpret_cast<f32x4*>(out + ((size_t)t1*BATCH + lane)*HID + wg*4) = ho;
            else            ho_keep = ho;  // defer: h0ring may alias d_out upper half
            drain_vmem();
        }

        __syncthreads();   // #3: all stores drained -> flag release safe
        if (tid == 0)
            __hip_atomic_store(&flags[wg*32], k + 1, __ATOMIC_RELAXED, __HIP_MEMORY_SCOPE_AGENT);
    }

    // epilogue: all wgs past round 512's reads, then store out[511]
    if (wv == 3){
        if (wg == 0) aggregate_publish(flags, SEQ + 1, lane);
        else         wait_epoch_g(flags, SEQ + 1, rep);
        lds_publish(&lds_epoch, SEQ + 1);
    }
    if (wv == 1){
        lds_wait(&lds_epoch, SEQ + 1);
        *reinterpret_cast<f32x4*>(out + ((size_t)(SEQ-1)*BATCH + lane)*HID + wg*4) = ho_keep;
    }
}

// ---------------- host launcher ----------------

extern "C" void kernel_launch(void* const* d_in, const int* in_sizes, int n_in,
                              void* d_out, int out_size, void* d_ws, size_t ws_size,
                              hipStream_t stream){
    const float* x   = (const float*)d_in[0];
    const float* Wx0 = (const float*)d_in[1];
    const float* bx0 = (const float*)d_in[2];
    const float* Wh0 = (const float*)d_in[3];
    const float* bh0 = (const float*)d_in[4];
    const float* Wx1 = (const float*)d_in[5];
    const float* bx1 = (const float*)d_in[6];
    const float* Wh1 = (const float*)d_in[7];
    const float* bh1 = (const float*)d_in[8];
    float* out = (float*)d_out;
    char* ws = (char*)d_ws;

    size_t o = 0;
    _Float16* Wr0 = (_Float16*)(ws + o); o += (size_t)NG*KCAT*2;          // 16 MB
    _Float16* Wr1 = (_Float16*)(ws + o); o += (size_t)NG*KCAT*2;          // 16 MB
    float* br0 = (float*)(ws + o); o += 16384;
    float* br1 = (float*)(ws + o); o += 16384;
    _Float16* h1ring = (_Float16*)(ws + o); o += (size_t)SEQ*BATCH*HID*2; // 64 MB
    _Float16* hz     = (_Float16*)(ws + o); o += (size_t)BATCH*HID*2;     // 128 KB
    int* flags = (int*)(ws + o); o += 65536;

    const size_t RING = (size_t)SEQ*BATCH*HID*2;                          // 64 MB
    _Float16 *xbf = nullptr, *h0ring;
    int use_xf16 = 0;
    if (ws_size >= o + 2*RING){                 // both in ws
        xbf    = (_Float16*)(ws + o);  o += RING;  use_xf16 = 1;
        h0ring = (_Float16*)(ws + o);  o += RING;
    } else if (ws_size >= o + RING){            // xbf in ws, h0ring -> d_out upper
        xbf    = (_Float16*)(ws + o);  o += RING;  use_xf16 = 1;
        h0ring = (_Float16*)((char*)d_out + (size_t)64*1024*1024);
    } else {                                    // f32 x path, h0ring -> d_out upper
        h0ring = (_Float16*)((char*)d_out + (size_t)64*1024*1024);
    }
    // h0ring<->d_out-upper alias safety: h0 slot k == out[256+k/2]; out[256+s]
    // written round 257+s; epoch order puts every wg >= round 256+s by then,
    // past h0[2s+1]'s last read (round 2s+2); only out[511] collides -> deferred.

    prep_w_kernel<<<NG, 256, 0, stream>>>(Wx0, Wh0, bx0, bh0, Wr0, br0);
    prep_w_kernel<<<NG, 256, 0, stream>>>(Wx1, Wh1, bx1, bh1, Wr1, br1);
    if (use_xf16)
        prep_x_kernel<<<(SEQ*BATCH*HID)/(256*8), 256, 0, stream>>>(x, xbf);
    init_misc_kernel<<<64, 256, 0, stream>>>(flags, hz);
    lstm_persist<<<256, 256, 0, stream>>>(Wr0, Wr1, br0, br1, xbf, x, use_xf16,
                                          hz, h0ring, h1ring, out, flags);
}

// Round 7
// 9837.792 us; speedup vs baseline: 2.0747x; 1.1074x over previous
//
#include <hip/hip_runtime.h>

// LSTM 2-layer, S=512 B=64 IN=H=1024, fp32 I/O, fp16 MFMA compute.
// R7 = R6 + recurrent-path weights staged in LDS (133 KB dynamic):
//   per-XCD weight L2 footprint was 4 MB (= capacity) -> streams evicted it
//   every round -> 8.3 GB FETCH. Now: layer0 h-cols (32KB) + layer1 (64KB)
//   live in LDS (XOR-swizzled, conflict-free ds_read_b128); only the
//   dep-free x-weights (1 MB/XCD) stay in L2.
// Structure unchanged: persistent 256 wg x 256 thr; round k = layer0 step k +
// layer1 step k-1; epoch tree (per-wg flags -> aggregator -> 8 replicas ->
// LDS mirror); h via sc0|sc1 stores into full-length rings; no fences.

#define SEQ   512
#define BATCH 64
#define HID   1024
#define NG    4096           // 4*HID
#define KCAT  2048           // IN + HID
#define EPOCH_IDX 8192       // flags[] base index of the 8 epoch replica lines

// dynamic LDS layout (bytes):
//   [0,32768)       Wh0: layer0 h-cols, 16 rows x 2048B, swizzled
//   [32768,98304)   W1 : layer1 all cols, 16 rows x 4096B, swizzled
//   [98304,133120)  accL: float[2][4][64][17]
//   [133120,133124) lds_epoch
#define SMEM_BYTES 133504

typedef __attribute__((ext_vector_type(8))) _Float16 f16x8;
typedef __attribute__((ext_vector_type(4))) _Float16 f16x4;
typedef __attribute__((ext_vector_type(4))) float    f32x4;

__device__ __forceinline__ float sigm_f(float x){ return 1.f/(1.f + __expf(-x)); }
__device__ __forceinline__ float tanh_f(float x){
    float e = __expf(-2.f*fabsf(x));
    float r = (1.f - e)/(1.f + e);
    return copysignf(r, x);
}

__device__ __forceinline__ void store_h8(_Float16* p, f16x4 v){
    asm volatile("global_store_dwordx2 %0, %1, off sc0 sc1" :: "v"(p), "v"(v) : "memory");
}
__device__ __forceinline__ void drain_vmem(){
    asm volatile("s_waitcnt vmcnt(0)" ::: "memory");
}

// ---------------- prep kernels ----------------

__global__ void prep_w_kernel(const float* __restrict__ Wx, const float* __restrict__ Wh,
                              const float* __restrict__ bx, const float* __restrict__ bh,
                              _Float16* __restrict__ Wr, float* __restrict__ br){
    int p = blockIdx.x;            // 0..4095 reordered row
    int j = p >> 2, g = p & 3;
    int r = g*1024 + j;            // original row in Wx/Wh
    int k = threadIdx.x * 8;       // 0..2040
    const float* s = (k < 1024) ? (Wx + (size_t)r*1024 + k)
                                : (Wh + (size_t)r*1024 + (k - 1024));
    float4 v0 = *reinterpret_cast<const float4*>(s);
    float4 v1 = *reinterpret_cast<const float4*>(s + 4);
    f16x8 o;
    o[0]=(_Float16)v0.x; o[1]=(_Float16)v0.y; o[2]=(_Float16)v0.z; o[3]=(_Float16)v0.w;
    o[4]=(_Float16)v1.x; o[5]=(_Float16)v1.y; o[6]=(_Float16)v1.z; o[7]=(_Float16)v1.w;
    *reinterpret_cast<f16x8*>(Wr + (size_t)p*KCAT + k) = o;
    if (threadIdx.x == 0) br[p] = bx[r] + bh[r];
}

__global__ void prep_x_kernel(const float* __restrict__ x, _Float16* xo){
    size_t i = ((size_t)blockIdx.x*256 + threadIdx.x) * 8;
    float4 v0 = *reinterpret_cast<const float4*>(x + i);
    float4 v1 = *reinterpret_cast<const float4*>(x + i + 4);
    f16x8 o;
    o[0]=(_Float16)v0.x; o[1]=(_Float16)v0.y; o[2]=(_Float16)v0.z; o[3]=(_Float16)v0.w;
    o[4]=(_Float16)v1.x; o[5]=(_Float16)v1.y; o[6]=(_Float16)v1.z; o[7]=(_Float16)v1.w;
    *reinterpret_cast<f16x8*>(xo + i) = o;
}

__global__ void init_misc_kernel(int* flags, _Float16* hz){
    int i = blockIdx.x*256 + threadIdx.x;            // 16384 threads
    flags[i] = 0;
    size_t j = (size_t)i * 4;
    if (j < (size_t)BATCH*HID){
        f16x4 z; z[0]=(_Float16)0.f; z[1]=(_Float16)0.f; z[2]=(_Float16)0.f; z[3]=(_Float16)0.f;
        *reinterpret_cast<f16x4*>(hz + j) = z;
    }
}

// ---------------- sync helpers (no fences) ----------------

__device__ __forceinline__ void wait_epoch_g(const int* flags, int k, int rep){
    for(;;){
        int e = __hip_atomic_load(&flags[EPOCH_IDX + rep*32], __ATOMIC_RELAXED, __HIP_MEMORY_SCOPE_AGENT);
        if (e >= k) break;
        __builtin_amdgcn_s_sleep(2);
    }
    asm volatile("" ::: "memory");
}

__device__ __forceinline__ void aggregate_publish(int* flags, int k, int lane){
    const int b = lane*4;
    for(;;){
        int a0 = __hip_atomic_load(&flags[(b+0)*32], __ATOMIC_RELAXED, __HIP_MEMORY_SCOPE_AGENT);
        int a1 = __hip_atomic_load(&flags[(b+1)*32], __ATOMIC_RELAXED, __HIP_MEMORY_SCOPE_AGENT);
        int a2 = __hip_atomic_load(&flags[(b+2)*32], __ATOMIC_RELAXED, __HIP_MEMORY_SCOPE_AGENT);
        int a3 = __hip_atomic_load(&flags[(b+3)*32], __ATOMIC_RELAXED, __HIP_MEMORY_SCOPE_AGENT);
        bool ok = (a0>=k) && (a1>=k) && (a2>=k) && (a3>=k);
        if (__all(ok)) break;
        __builtin_amdgcn_s_sleep(1);
    }
    asm volatile("" ::: "memory");
    if (lane < 8)
        __hip_atomic_store(&flags[EPOCH_IDX + lane*32], k, __ATOMIC_RELAXED, __HIP_MEMORY_SCOPE_AGENT);
}

__device__ __forceinline__ void lds_publish(int* e, int k){
    __hip_atomic_store(e, k, __ATOMIC_RELAXED, __HIP_MEMORY_SCOPE_WORKGROUP);
}
__device__ __forceinline__ void lds_wait(int* e, int k){
    while (__hip_atomic_load(e, __ATOMIC_RELAXED, __HIP_MEMORY_SCOPE_WORKGROUP) < k)
        __builtin_amdgcn_s_sleep(1);
    asm volatile("" ::: "memory");
}

// ---------------- GEMM quarter helpers ----------------

__device__ __forceinline__ f32x4 mfma16(f16x8 a, f16x8 b, f32x4 c){
    return __builtin_amdgcn_mfma_f32_16x16x32_f16(a, b, c, 0, 0, 0);
}

// B from global (x-weights)
__device__ __forceinline__ void gemm_q_f16(const _Float16* A, const _Float16* Wp, f32x4* acc){
    #pragma unroll 4
    for (int kk = 0; kk < 16; ++kk){
        f16x8 b  = *reinterpret_cast<const f16x8*>(Wp + kk*32);
        f16x8 a0 = *reinterpret_cast<const f16x8*>(A + kk*32);
        f16x8 a1 = *reinterpret_cast<const f16x8*>(A + kk*32 + 16*1024);
        f16x8 a2 = *reinterpret_cast<const f16x8*>(A + kk*32 + 32*1024);
        f16x8 a3 = *reinterpret_cast<const f16x8*>(A + kk*32 + 48*1024);
        acc[0] = mfma16(a0, b, acc[0]);
        acc[1] = mfma16(a1, b, acc[1]);
        acc[2] = mfma16(a2, b, acc[2]);
        acc[3] = mfma16(a3, b, acc[3]);
    }
}

__device__ __forceinline__ void gemm_q_f32(const float* A, const _Float16* Wp, f32x4* acc){
    #pragma unroll 2
    for (int kk = 0; kk < 16; ++kk){
        f16x8 b = *reinterpret_cast<const f16x8*>(Wp + kk*32);
        f16x8 a[4];
        #pragma unroll
        for (int m = 0; m < 4; ++m){
            float4 u0 = *reinterpret_cast<const float4*>(A + kk*32 + (size_t)m*16*1024);
            float4 u1 = *reinterpret_cast<const float4*>(A + kk*32 + (size_t)m*16*1024 + 4);
            f16x8 v;
            v[0]=(_Float16)u0.x; v[1]=(_Float16)u0.y; v[2]=(_Float16)u0.z; v[3]=(_Float16)u0.w;
            v[4]=(_Float16)u1.x; v[5]=(_Float16)u1.y; v[6]=(_Float16)u1.z; v[7]=(_Float16)u1.w;
            a[m] = v;
        }
        acc[0] = mfma16(a[0], b, acc[0]);
        acc[1] = mfma16(a[1], b, acc[1]);
        acc[2] = mfma16(a[2], b, acc[2]);
        acc[3] = mfma16(a[3], b, acc[3]);
    }
}

// B from LDS (recurrent weights); wrow = region + r*stride; c0 = lane col-byte;
// swizzle applied per-kk because kk*64 carries into bit 6.
__device__ __forceinline__ void gemm_q_ldsb(const _Float16* A, const char* wrow,
                                            int c0, int swz, f32x4* acc){
    #pragma unroll 4
    for (int kk = 0; kk < 16; ++kk){
        f16x8 b  = *reinterpret_cast<const f16x8*>(wrow + ((c0 + kk*64) ^ swz));
        f16x8 a0 = *reinterpret_cast<const f16x8*>(A + kk*32);
        f16x8 a1 = *reinterpret_cast<const f16x8*>(A + kk*32 + 16*1024);
        f16x8 a2 = *reinterpret_cast<const f16x8*>(A + kk*32 + 32*1024);
        f16x8 a3 = *reinterpret_cast<const f16x8*>(A + kk*32 + 48*1024);
        acc[0] = mfma16(a0, b, acc[0]);
        acc[1] = mfma16(a1, b, acc[1]);
        acc[2] = mfma16(a2, b, acc[2]);
        acc[3] = mfma16(a3, b, acc[3]);
    }
}

// ---------------- persistent LSTM kernel ----------------

__global__ __launch_bounds__(256, 1)
void lstm_persist(const _Float16* __restrict__ Wr0, const _Float16* __restrict__ Wr1,
                  const float* __restrict__ br0, const float* __restrict__ br1,
                  const _Float16* __restrict__ xbf, const float* __restrict__ xf32,
                  int use_xf16, const _Float16* __restrict__ hz,
                  _Float16* h0ring, _Float16* h1ring, float* out, int* flags){
    extern __shared__ char smem[];
    float (*accL)[4][64][17] = reinterpret_cast<float(*)[4][64][17]>(smem + 98304);
    int* lds_epoch = reinterpret_cast<int*>(smem + 133120);

    const int tid  = threadIdx.x;
    const int wg   = blockIdx.x;          // 0..255
    const int wv   = tid >> 6;            // wave 0..3
    const int lane = tid & 63;
    const int r    = lane & 15;
    const int q    = lane >> 4;
    const int p0   = wg * 16;             // gate-row base (16 rows = 4 h-cols)
    const int rep  = wg & 7;
    const int swz  = (r & 7) << 4;

    // ---- stage recurrent-path weights into LDS (once) ----
    for (int idx = tid; idx < 6144; idx += 256){
        int rr, cb; char* dst; const _Float16* s;
        if (idx < 2048){                         // Wh0: layer0 cols 1024..2047
            rr = idx >> 7;  cb = (idx & 127) << 4;
            s   = Wr0 + (size_t)(p0 + rr)*KCAT + 1024 + (cb >> 1);
            dst = smem + rr*2048 + (cb ^ ((rr & 7) << 4));
        } else {                                 // W1: layer1 cols 0..2047
            int j2 = idx - 2048;
            rr = j2 >> 8;  cb = (j2 & 255) << 4;
            s   = Wr1 + (size_t)(p0 + rr)*KCAT + (cb >> 1);
            dst = smem + 32768 + rr*4096 + (cb ^ ((rr & 7) << 4));
        }
        *reinterpret_cast<f16x8*>(dst) = *reinterpret_cast<const f16x8*>(s);
    }
    if (tid == 0) *lds_epoch = 0;
    __syncthreads();

    f32x4 cst = {0.f,0.f,0.f,0.f};        // wave0: c(layer0); wave1: c(layer1)
    f32x4 ho_keep = {0.f,0.f,0.f,0.f};    // wave1: out[511] deferred
    f32x4 bias[4];
    {
        const float* bsrc = (wv == 0) ? br0 : br1;
        #pragma unroll
        for (int jj = 0; jj < 4; ++jj)
            bias[jj] = *reinterpret_cast<const f32x4*>(&bsrc[p0 + jj*4]);
    }

    const int kofs = (wv & 1)*512 + q*8;  // A k-offset within 1024-half
    const int wcol = wv*512 + q*8;        // weight k-column (elements, global path)
    const char* w1row  = smem + 32768 + r*4096;   // layer1 LDS row base
    const char* wh0row = smem + r*2048;           // layer0 h-cols LDS row base

    for (int k = 0; k <= SEQ; ++k){
        f32x4 acc0[4], acc1[4];
        #pragma unroll
        for (int m = 0; m < 4; ++m){
            acc0[m].x=0;acc0[m].y=0;acc0[m].z=0;acc0[m].w=0;
            acc1[m].x=0;acc1[m].y=0;acc1[m].z=0;acc1[m].w=0;
        }

        if (wv < 2){
            // dep-free x-GEMM first (global x-weights), then epoch wait, then
            // layer1's h0-input GEMM (LDS weights, cols 0..1023)
            if (k < SEQ){
                if (use_xf16)
                    gemm_q_f16(xbf + (size_t)k*BATCH*HID + (size_t)r*HID + kofs,
                               Wr0 + (size_t)(p0 + r)*KCAT + wcol, acc0);
                else
                    gemm_q_f32(xf32 + (size_t)k*BATCH*1024 + (size_t)r*1024 + kofs,
                               Wr0 + (size_t)(p0 + r)*KCAT + wcol, acc0);
            }
            if (k > 0){
                lds_wait(lds_epoch, k);
                gemm_q_ldsb(h0ring + (size_t)(k-1)*BATCH*HID + (size_t)r*HID + kofs,
                            w1row, wv*1024 + q*16, swz, acc1);
            }
        } else {
            if (k > 0){
                if (wv == 3){
                    if (wg == 0) aggregate_publish(flags, k, lane);
                    else         wait_epoch_g(flags, k, rep);
                    lds_publish(lds_epoch, k);
                } else {
                    lds_wait(lds_epoch, k);
                }
            }
            if (k < SEQ){   // layer0 h-GEMM, LDS weights (cols 1024..2047)
                const _Float16* A0 = (k == 0) ? (hz + (size_t)r*HID + kofs)
                                              : (h0ring + (size_t)(k-1)*BATCH*HID + (size_t)r*HID + kofs);
                gemm_q_ldsb(A0, wh0row, (wv-2)*1024 + q*16, swz, acc0);
            }
            if (k >= 1){    // layer1 h1-GEMM, LDS weights (cols 1024..2047)
                const _Float16* A1 = (k == 1) ? (hz + (size_t)r*HID + kofs)
                                              : (h1ring + (size_t)(k-2)*BATCH*HID + (size_t)r*HID + kofs);
                gemm_q_ldsb(A1, w1row, wv*1024 + q*16, swz, acc1);
            }
        }

        __syncthreads();   // #1: prev round's elementwise LDS reads complete

        #pragma unroll
        for (int mt = 0; mt < 4; ++mt){
            #pragma unroll
            for (int j = 0; j < 4; ++j){
                accL[0][wv][mt*16 + q*4 + j][r] = acc0[mt][j];
                accL[1][wv][mt*16 + q*4 + j][r] = acc1[mt][j];
            }
        }
        __syncthreads();   // #2: partials visible

        if (wv == 0 && k < SEQ){
            f32x4 zz[4];
            #pragma unroll
            for (int jj = 0; jj < 4; ++jj) zz[jj] = bias[jj];
            #pragma unroll
            for (int w2 = 0; w2 < 4; ++w2)
                #pragma unroll
                for (int jj = 0; jj < 4; ++jj){
                    f32x4 a = *reinterpret_cast<const f32x4*>(&accL[0][w2][lane][jj*4]);
                    zz[jj].x += a.x; zz[jj].y += a.y; zz[jj].z += a.z; zz[jj].w += a.w;
                }
            f16x4 hv;
            #pragma unroll
            for (int jl = 0; jl < 4; ++jl){
                float ig = sigm_f(zz[jl].x), fg = sigm_f(zz[jl].y);
                float gg = tanh_f(zz[jl].z), og = sigm_f(zz[jl].w);
                float c = fg*cst[jl] + ig*gg;  cst[jl] = c;
                hv[jl] = (_Float16)(og * tanh_f(c));
            }
            store_h8(h0ring + ((size_t)k*BATCH + lane)*HID + wg*4, hv);
            drain_vmem();
        }
        if (wv == 1 && k >= 1){
            const int t1 = k - 1;
            f32x4 zz[4];
            #pragma unroll
            for (int jj = 0; jj < 4; ++jj) zz[jj] = bias[jj];
            #pragma unroll
            for (int w2 = 0; w2 < 4; ++w2)
                #pragma unroll
                for (int jj = 0; jj < 4; ++jj){
                    f32x4 a = *reinterpret_cast<const f32x4*>(&accL[1][w2][lane][jj*4]);
                    zz[jj].x += a.x; zz[jj].y += a.y; zz[jj].z += a.z; zz[jj].w += a.w;
                }
            f16x4 hv; f32x4 ho;
            #pragma unroll
            for (int jl = 0; jl < 4; ++jl){
                float ig = sigm_f(zz[jl].x), fg = sigm_f(zz[jl].y);
                float gg = tanh_f(zz[jl].z), og = sigm_f(zz[jl].w);
                float c = fg*cst[jl] + ig*gg;  cst[jl] = c;
                float h = og * tanh_f(c);
                hv[jl] = (_Float16)h;  ho[jl] = h;
            }
            if (k < SEQ) store_h8(h1ring + ((size_t)t1*BATCH + lane)*HID + wg*4, hv);
            if (t1 < SEQ-1) *reinterpret_cast<f32x4*>(out + ((size_t)t1*BATCH + lane)*HID + wg*4) = ho;
            else            ho_keep = ho;  // defer: h0ring may alias d_out upper half
            drain_vmem();
        }

        __syncthreads();   // #3: all stores drained -> flag release safe
        if (tid == 0)
            __hip_atomic_store(&flags[wg*32], k + 1, __ATOMIC_RELAXED, __HIP_MEMORY_SCOPE_AGENT);
    }

    // epilogue: all wgs past round 512's reads, then store out[511]
    if (wv == 3){
        if (wg == 0) aggregate_publish(flags, SEQ + 1, lane);
        else         wait_epoch_g(flags, SEQ + 1, rep);
        lds_publish(lds_epoch, SEQ + 1);
    }
    if (wv == 1){
        lds_wait(lds_epoch, SEQ + 1);
        *reinterpret_cast<f32x4*>(out + ((size_t)(SEQ-1)*BATCH + lane)*HID + wg*4) = ho_keep;
    }
}

// ---------------- host launcher ----------------

extern "C" void kernel_launch(void* const* d_in, const int* in_sizes, int n_in,
                              void* d_out, int out_size, void* d_ws, size_t ws_size,
                              hipStream_t stream){
    const float* x   = (const float*)d_in[0];
    const float* Wx0 = (const float*)d_in[1];
    const float* bx0 = (const float*)d_in[2];
    const float* Wh0 = (const float*)d_in[3];
    const float* bh0 = (const float*)d_in[4];
    const float* Wx1 = (const float*)d_in[5];
    const float* bx1 = (const float*)d_in[6];
    const float* Wh1 = (const float*)d_in[7];
    const float* bh1 = (const float*)d_in[8];
    float* out = (float*)d_out;
    char* ws = (char*)d_ws;

    size_t o = 0;
    _Float16* Wr0 = (_Float16*)(ws + o); o += (size_t)NG*KCAT*2;          // 16 MB
    _Float16* Wr1 = (_Float16*)(ws + o); o += (size_t)NG*KCAT*2;          // 16 MB
    float* br0 = (float*)(ws + o); o += 16384;
    float* br1 = (float*)(ws + o); o += 16384;
    _Float16* h1ring = (_Float16*)(ws + o); o += (size_t)SEQ*BATCH*HID*2; // 64 MB
    _Float16* hz     = (_Float16*)(ws + o); o += (size_t)BATCH*HID*2;     // 128 KB
    int* flags = (int*)(ws + o); o += 65536;

    const size_t RING = (size_t)SEQ*BATCH*HID*2;                          // 64 MB
    _Float16 *xbf = nullptr, *h0ring;
    int use_xf16 = 0;
    if (ws_size >= o + 2*RING){
        xbf    = (_Float16*)(ws + o);  o += RING;  use_xf16 = 1;
        h0ring = (_Float16*)(ws + o);  o += RING;
    } else if (ws_size >= o + RING){
        xbf    = (_Float16*)(ws + o);  o += RING;  use_xf16 = 1;
        h0ring = (_Float16*)((char*)d_out + (size_t)64*1024*1024);
    } else {
        h0ring = (_Float16*)((char*)d_out + (size_t)64*1024*1024);
    }
    // h0ring<->d_out-upper alias safety: proven in R5/R6 (epoch-ordered;
    // only out[511] collides -> deferred past epoch 513).

    hipFuncSetAttribute((const void*)lstm_persist,
                        hipFuncAttributeMaxDynamicSharedMemorySize, SMEM_BYTES);

    prep_w_kernel<<<NG, 256, 0, stream>>>(Wx0, Wh0, bx0, bh0, Wr0, br0);
    prep_w_kernel<<<NG, 256, 0, stream>>>(Wx1, Wh1, bx1, bh1, Wr1, br1);
    if (use_xf16)
        prep_x_kernel<<<(SEQ*BATCH*HID)/(256*8), 256, 0, stream>>>(x, xbf);
    init_misc_kernel<<<64, 256, 0, stream>>>(flags, hz);
    lstm_persist<<<256, 256, SMEM_BYTES, stream>>>(Wr0, Wr1, br0, br1, xbf, x, use_xf16,
                                                   hz, h0ring, h1ring, out, flags);
}

// Round 8
// 9469.009 us; speedup vs baseline: 2.1555x; 1.0389x over previous
//
#include <hip/hip_runtime.h>

// LSTM 2-layer, S=512 B=64 IN=H=1024, fp32 I/O, fp16 MFMA compute.
// R8 = R7 + latency attack on the dependent-GEMM critical path:
//   (1) waves 2/3's two dependent GEMMs (L0h, L1h) fused into ONE loop:
//       8 independent A-loads/kk (vs 4), unroll 4 -> ~32 loads in flight.
//   (2) redundant __syncthreads #1 removed (sync#3 already orders accL).
//   (3) unroll 8 on the post-epoch single GEMM (wv0/1).
// Unchanged: LDS-resident recurrent weights (swizzled), epoch tree, sc0|sc1
// h rings, no fences in loop, h0ring may alias d_out upper half.

#define SEQ   512
#define BATCH 64
#define HID   1024
#define NG    4096           // 4*HID
#define KCAT  2048           // IN + HID
#define EPOCH_IDX 8192       // flags[] base index of the 8 epoch replica lines

// dynamic LDS layout (bytes):
//   [0,32768)       Wh0: layer0 h-cols, 16 rows x 2048B, swizzled
//   [32768,98304)   W1 : layer1 all cols, 16 rows x 4096B, swizzled
//   [98304,133120)  accL: float[2][4][64][17]
//   [133120,133124) lds_epoch
#define SMEM_BYTES 133504

typedef __attribute__((ext_vector_type(8))) _Float16 f16x8;
typedef __attribute__((ext_vector_type(4))) _Float16 f16x4;
typedef __attribute__((ext_vector_type(4))) float    f32x4;

__device__ __forceinline__ float sigm_f(float x){ return 1.f/(1.f + __expf(-x)); }
__device__ __forceinline__ float tanh_f(float x){
    float e = __expf(-2.f*fabsf(x));
    float r = (1.f - e)/(1.f + e);
    return copysignf(r, x);
}

__device__ __forceinline__ void store_h8(_Float16* p, f16x4 v){
    asm volatile("global_store_dwordx2 %0, %1, off sc0 sc1" :: "v"(p), "v"(v) : "memory");
}
__device__ __forceinline__ void drain_vmem(){
    asm volatile("s_waitcnt vmcnt(0)" ::: "memory");
}

// ---------------- prep kernels ----------------

__global__ void prep_w_kernel(const float* __restrict__ Wx, const float* __restrict__ Wh,
                              const float* __restrict__ bx, const float* __restrict__ bh,
                              _Float16* __restrict__ Wr, float* __restrict__ br){
    int p = blockIdx.x;            // 0..4095 reordered row
    int j = p >> 2, g = p & 3;
    int r = g*1024 + j;            // original row in Wx/Wh
    int k = threadIdx.x * 8;       // 0..2040
    const float* s = (k < 1024) ? (Wx + (size_t)r*1024 + k)
                                : (Wh + (size_t)r*1024 + (k - 1024));
    float4 v0 = *reinterpret_cast<const float4*>(s);
    float4 v1 = *reinterpret_cast<const float4*>(s + 4);
    f16x8 o;
    o[0]=(_Float16)v0.x; o[1]=(_Float16)v0.y; o[2]=(_Float16)v0.z; o[3]=(_Float16)v0.w;
    o[4]=(_Float16)v1.x; o[5]=(_Float16)v1.y; o[6]=(_Float16)v1.z; o[7]=(_Float16)v1.w;
    *reinterpret_cast<f16x8*>(Wr + (size_t)p*KCAT + k) = o;
    if (threadIdx.x == 0) br[p] = bx[r] + bh[r];
}

__global__ void prep_x_kernel(const float* __restrict__ x, _Float16* xo){
    size_t i = ((size_t)blockIdx.x*256 + threadIdx.x) * 8;
    float4 v0 = *reinterpret_cast<const float4*>(x + i);
    float4 v1 = *reinterpret_cast<const float4*>(x + i + 4);
    f16x8 o;
    o[0]=(_Float16)v0.x; o[1]=(_Float16)v0.y; o[2]=(_Float16)v0.z; o[3]=(_Float16)v0.w;
    o[4]=(_Float16)v1.x; o[5]=(_Float16)v1.y; o[6]=(_Float16)v1.z; o[7]=(_Float16)v1.w;
    *reinterpret_cast<f16x8*>(xo + i) = o;
}

__global__ void init_misc_kernel(int* flags, _Float16* hz){
    int i = blockIdx.x*256 + threadIdx.x;            // 16384 threads
    flags[i] = 0;
    size_t j = (size_t)i * 4;
    if (j < (size_t)BATCH*HID){
        f16x4 z; z[0]=(_Float16)0.f; z[1]=(_Float16)0.f; z[2]=(_Float16)0.f; z[3]=(_Float16)0.f;
        *reinterpret_cast<f16x4*>(hz + j) = z;
    }
}

// ---------------- sync helpers (no fences) ----------------

__device__ __forceinline__ void wait_epoch_g(const int* flags, int k, int rep){
    for(;;){
        int e = __hip_atomic_load(&flags[EPOCH_IDX + rep*32], __ATOMIC_RELAXED, __HIP_MEMORY_SCOPE_AGENT);
        if (e >= k) break;
        __builtin_amdgcn_s_sleep(2);
    }
    asm volatile("" ::: "memory");
}

__device__ __forceinline__ void aggregate_publish(int* flags, int k, int lane){
    const int b = lane*4;
    for(;;){
        int a0 = __hip_atomic_load(&flags[(b+0)*32], __ATOMIC_RELAXED, __HIP_MEMORY_SCOPE_AGENT);
        int a1 = __hip_atomic_load(&flags[(b+1)*32], __ATOMIC_RELAXED, __HIP_MEMORY_SCOPE_AGENT);
        int a2 = __hip_atomic_load(&flags[(b+2)*32], __ATOMIC_RELAXED, __HIP_MEMORY_SCOPE_AGENT);
        int a3 = __hip_atomic_load(&flags[(b+3)*32], __ATOMIC_RELAXED, __HIP_MEMORY_SCOPE_AGENT);
        bool ok = (a0>=k) && (a1>=k) && (a2>=k) && (a3>=k);
        if (__all(ok)) break;
        __builtin_amdgcn_s_sleep(1);
    }
    asm volatile("" ::: "memory");
    if (lane < 8)
        __hip_atomic_store(&flags[EPOCH_IDX + lane*32], k, __ATOMIC_RELAXED, __HIP_MEMORY_SCOPE_AGENT);
}

__device__ __forceinline__ void lds_publish(int* e, int k){
    __hip_atomic_store(e, k, __ATOMIC_RELAXED, __HIP_MEMORY_SCOPE_WORKGROUP);
}
__device__ __forceinline__ void lds_wait(int* e, int k){
    while (__hip_atomic_load(e, __ATOMIC_RELAXED, __HIP_MEMORY_SCOPE_WORKGROUP) < k)
        __builtin_amdgcn_s_sleep(1);
    asm volatile("" ::: "memory");
}

// ---------------- GEMM quarter helpers ----------------

__device__ __forceinline__ f32x4 mfma16(f16x8 a, f16x8 b, f32x4 c){
    return __builtin_amdgcn_mfma_f32_16x16x32_f16(a, b, c, 0, 0, 0);
}

// B from global (x-weights)
__device__ __forceinline__ void gemm_q_f16(const _Float16* A, const _Float16* Wp, f32x4* acc){
    #pragma unroll 4
    for (int kk = 0; kk < 16; ++kk){
        f16x8 b  = *reinterpret_cast<const f16x8*>(Wp + kk*32);
        f16x8 a0 = *reinterpret_cast<const f16x8*>(A + kk*32);
        f16x8 a1 = *reinterpret_cast<const f16x8*>(A + kk*32 + 16*1024);
        f16x8 a2 = *reinterpret_cast<const f16x8*>(A + kk*32 + 32*1024);
        f16x8 a3 = *reinterpret_cast<const f16x8*>(A + kk*32 + 48*1024);
        acc[0] = mfma16(a0, b, acc[0]);
        acc[1] = mfma16(a1, b, acc[1]);
        acc[2] = mfma16(a2, b, acc[2]);
        acc[3] = mfma16(a3, b, acc[3]);
    }
}

__device__ __forceinline__ void gemm_q_f32(const float* A, const _Float16* Wp, f32x4* acc){
    #pragma unroll 2
    for (int kk = 0; kk < 16; ++kk){
        f16x8 b = *reinterpret_cast<const f16x8*>(Wp + kk*32);
        f16x8 a[4];
        #pragma unroll
        for (int m = 0; m < 4; ++m){
            float4 u0 = *reinterpret_cast<const float4*>(A + kk*32 + (size_t)m*16*1024);
            float4 u1 = *reinterpret_cast<const float4*>(A + kk*32 + (size_t)m*16*1024 + 4);
            f16x8 v;
            v[0]=(_Float16)u0.x; v[1]=(_Float16)u0.y; v[2]=(_Float16)u0.z; v[3]=(_Float16)u0.w;
            v[4]=(_Float16)u1.x; v[5]=(_Float16)u1.y; v[6]=(_Float16)u1.z; v[7]=(_Float16)u1.w;
            a[m] = v;
        }
        acc[0] = mfma16(a[0], b, acc[0]);
        acc[1] = mfma16(a[1], b, acc[1]);
        acc[2] = mfma16(a[2], b, acc[2]);
        acc[3] = mfma16(a[3], b, acc[3]);
    }
}

// single GEMM, B from LDS (post-epoch path on wv0/1) — deeper unroll for MLP
__device__ __forceinline__ void gemm_q_ldsb(const _Float16* A, const char* wrow,
                                            int c0, int swz, f32x4* acc){
    #pragma unroll 8
    for (int kk = 0; kk < 16; ++kk){
        f16x8 b  = *reinterpret_cast<const f16x8*>(wrow + ((c0 + kk*64) ^ swz));
        f16x8 a0 = *reinterpret_cast<const f16x8*>(A + kk*32);
        f16x8 a1 = *reinterpret_cast<const f16x8*>(A + kk*32 + 16*1024);
        f16x8 a2 = *reinterpret_cast<const f16x8*>(A + kk*32 + 32*1024);
        f16x8 a3 = *reinterpret_cast<const f16x8*>(A + kk*32 + 48*1024);
        acc[0] = mfma16(a0, b, acc[0]);
        acc[1] = mfma16(a1, b, acc[1]);
        acc[2] = mfma16(a2, b, acc[2]);
        acc[3] = mfma16(a3, b, acc[3]);
    }
}

// FUSED dual GEMM (wv2/3 critical path): 8 independent A-loads per kk.
__device__ __forceinline__ void gemm_dual_ldsb(const _Float16* A0, const _Float16* A1,
                                               const char* w0row, int c00,
                                               const char* w1row, int c01, int swz,
                                               f32x4* acc0, f32x4* acc1){
    #pragma unroll 4
    for (int kk = 0; kk < 16; ++kk){
        f16x8 x0 = *reinterpret_cast<const f16x8*>(A0 + kk*32);
        f16x8 x1 = *reinterpret_cast<const f16x8*>(A0 + kk*32 + 16*1024);
        f16x8 x2 = *reinterpret_cast<const f16x8*>(A0 + kk*32 + 32*1024);
        f16x8 x3 = *reinterpret_cast<const f16x8*>(A0 + kk*32 + 48*1024);
        f16x8 y0 = *reinterpret_cast<const f16x8*>(A1 + kk*32);
        f16x8 y1 = *reinterpret_cast<const f16x8*>(A1 + kk*32 + 16*1024);
        f16x8 y2 = *reinterpret_cast<const f16x8*>(A1 + kk*32 + 32*1024);
        f16x8 y3 = *reinterpret_cast<const f16x8*>(A1 + kk*32 + 48*1024);
        f16x8 b0 = *reinterpret_cast<const f16x8*>(w0row + ((c00 + kk*64) ^ swz));
        f16x8 b1 = *reinterpret_cast<const f16x8*>(w1row + ((c01 + kk*64) ^ swz));
        acc0[0] = mfma16(x0, b0, acc0[0]);
        acc0[1] = mfma16(x1, b0, acc0[1]);
        acc0[2] = mfma16(x2, b0, acc0[2]);
        acc0[3] = mfma16(x3, b0, acc0[3]);
        acc1[0] = mfma16(y0, b1, acc1[0]);
        acc1[1] = mfma16(y1, b1, acc1[1]);
        acc1[2] = mfma16(y2, b1, acc1[2]);
        acc1[3] = mfma16(y3, b1, acc1[3]);
    }
}

// ---------------- persistent LSTM kernel ----------------

__global__ __launch_bounds__(256, 1)
void lstm_persist(const _Float16* __restrict__ Wr0, const _Float16* __restrict__ Wr1,
                  const float* __restrict__ br0, const float* __restrict__ br1,
                  const _Float16* __restrict__ xbf, const float* __restrict__ xf32,
                  int use_xf16, const _Float16* __restrict__ hz,
                  _Float16* h0ring, _Float16* h1ring, float* out, int* flags){
    extern __shared__ char smem[];
    float (*accL)[4][64][17] = reinterpret_cast<float(*)[4][64][17]>(smem + 98304);
    int* lds_epoch = reinterpret_cast<int*>(smem + 133120);

    const int tid  = threadIdx.x;
    const int wg   = blockIdx.x;          // 0..255
    const int wv   = tid >> 6;            // wave 0..3
    const int lane = tid & 63;
    const int r    = lane & 15;
    const int q    = lane >> 4;
    const int p0   = wg * 16;             // gate-row base (16 rows = 4 h-cols)
    const int rep  = wg & 7;
    const int swz  = (r & 7) << 4;

    // ---- stage recurrent-path weights into LDS (once) ----
    for (int idx = tid; idx < 6144; idx += 256){
        int rr, cb; char* dst; const _Float16* s;
        if (idx < 2048){                         // Wh0: layer0 cols 1024..2047
            rr = idx >> 7;  cb = (idx & 127) << 4;
            s   = Wr0 + (size_t)(p0 + rr)*KCAT + 1024 + (cb >> 1);
            dst = smem + rr*2048 + (cb ^ ((rr & 7) << 4));
        } else {                                 // W1: layer1 cols 0..2047
            int j2 = idx - 2048;
            rr = j2 >> 8;  cb = (j2 & 255) << 4;
            s   = Wr1 + (size_t)(p0 + rr)*KCAT + (cb >> 1);
            dst = smem + 32768 + rr*4096 + (cb ^ ((rr & 7) << 4));
        }
        *reinterpret_cast<f16x8*>(dst) = *reinterpret_cast<const f16x8*>(s);
    }
    if (tid == 0) *lds_epoch = 0;
    __syncthreads();

    f32x4 cst = {0.f,0.f,0.f,0.f};        // wave0: c(layer0); wave1: c(layer1)
    f32x4 ho_keep = {0.f,0.f,0.f,0.f};    // wave1: out[511] deferred
    f32x4 bias[4];
    {
        const float* bsrc = (wv == 0) ? br0 : br1;
        #pragma unroll
        for (int jj = 0; jj < 4; ++jj)
            bias[jj] = *reinterpret_cast<const f32x4*>(&bsrc[p0 + jj*4]);
    }

    const int kofs = (wv & 1)*512 + q*8;  // A k-offset within 1024-half
    const int wcol = wv*512 + q*8;        // weight k-column (elements, global path)
    const char* w1row  = smem + 32768 + r*4096;   // layer1 LDS row base
    const char* wh0row = smem + r*2048;           // layer0 h-cols LDS row base

    for (int k = 0; k <= SEQ; ++k){
        f32x4 acc0[4], acc1[4];
        #pragma unroll
        for (int m = 0; m < 4; ++m){
            acc0[m].x=0;acc0[m].y=0;acc0[m].z=0;acc0[m].w=0;
            acc1[m].x=0;acc1[m].y=0;acc1[m].z=0;acc1[m].w=0;
        }

        if (wv < 2){
            // dep-free x-GEMM first (global x-weights), then epoch wait, then
            // layer1's h0-input GEMM (LDS weights, cols 0..1023)
            if (k < SEQ){
                if (use_xf16)
                    gemm_q_f16(xbf + (size_t)k*BATCH*HID + (size_t)r*HID + kofs,
                               Wr0 + (size_t)(p0 + r)*KCAT + wcol, acc0);
                else
                    gemm_q_f32(xf32 + (size_t)k*BATCH*1024 + (size_t)r*1024 + kofs,
                               Wr0 + (size_t)(p0 + r)*KCAT + wcol, acc0);
            }
            if (k > 0){
                lds_wait(lds_epoch, k);
                gemm_q_ldsb(h0ring + (size_t)(k-1)*BATCH*HID + (size_t)r*HID + kofs,
                            w1row, wv*1024 + q*16, swz, acc1);
            }
        } else {
            if (k > 0){
                if (wv == 3){
                    if (wg == 0) aggregate_publish(flags, k, lane);
                    else         wait_epoch_g(flags, k, rep);
                    lds_publish(lds_epoch, k);
                } else {
                    lds_wait(lds_epoch, k);
                }
            }
            if (k > 0 && k < SEQ){
                // FUSED: layer0-h (A0=h0[k-1]) + layer1-h (A1=h1[k-2] or hz)
                const _Float16* A0 = h0ring + (size_t)(k-1)*BATCH*HID + (size_t)r*HID + kofs;
                const _Float16* A1 = (k == 1) ? (hz + (size_t)r*HID + kofs)
                                              : (h1ring + (size_t)(k-2)*BATCH*HID + (size_t)r*HID + kofs);
                gemm_dual_ldsb(A0, A1, wh0row, (wv-2)*1024 + q*16,
                               w1row, wv*1024 + q*16, swz, acc0, acc1);
            } else if (k == 0){
                gemm_q_ldsb(hz + (size_t)r*HID + kofs, wh0row, (wv-2)*1024 + q*16, swz, acc0);
            } else { // k == SEQ
                gemm_q_ldsb(h1ring + (size_t)(k-2)*BATCH*HID + (size_t)r*HID + kofs,
                            w1row, wv*1024 + q*16, swz, acc1);
            }
        }

        // (sync #1 removed: sync #3 of the previous round already ordered the
        //  elementwise accL reads before these writes)

        #pragma unroll
        for (int mt = 0; mt < 4; ++mt){
            #pragma unroll
            for (int j = 0; j < 4; ++j){
                accL[0][wv][mt*16 + q*4 + j][r] = acc0[mt][j];
                accL[1][wv][mt*16 + q*4 + j][r] = acc1[mt][j];
            }
        }
        __syncthreads();   // #2: partials visible

        if (wv == 0 && k < SEQ){
            f32x4 zz[4];
            #pragma unroll
            for (int jj = 0; jj < 4; ++jj) zz[jj] = bias[jj];
            #pragma unroll
            for (int w2 = 0; w2 < 4; ++w2)
                #pragma unroll
                for (int jj = 0; jj < 4; ++jj){
                    f32x4 a = *reinterpret_cast<const f32x4*>(&accL[0][w2][lane][jj*4]);
                    zz[jj].x += a.x; zz[jj].y += a.y; zz[jj].z += a.z; zz[jj].w += a.w;
                }
            f16x4 hv;
            #pragma unroll
            for (int jl = 0; jl < 4; ++jl){
                float ig = sigm_f(zz[jl].x), fg = sigm_f(zz[jl].y);
                float gg = tanh_f(zz[jl].z), og = sigm_f(zz[jl].w);
                float c = fg*cst[jl] + ig*gg;  cst[jl] = c;
                hv[jl] = (_Float16)(og * tanh_f(c));
            }
            store_h8(h0ring + ((size_t)k*BATCH + lane)*HID + wg*4, hv);
            drain_vmem();
        }
        if (wv == 1 && k >= 1){
            const int t1 = k - 1;
            f32x4 zz[4];
            #pragma unroll
            for (int jj = 0; jj < 4; ++jj) zz[jj] = bias[jj];
            #pragma unroll
            for (int w2 = 0; w2 < 4; ++w2)
                #pragma unroll
                for (int jj = 0; jj < 4; ++jj){
                    f32x4 a = *reinterpret_cast<const f32x4*>(&accL[1][w2][lane][jj*4]);
                    zz[jj].x += a.x; zz[jj].y += a.y; zz[jj].z += a.z; zz[jj].w += a.w;
                }
            f16x4 hv; f32x4 ho;
            #pragma unroll
            for (int jl = 0; jl < 4; ++jl){
                float ig = sigm_f(zz[jl].x), fg = sigm_f(zz[jl].y);
                float gg = tanh_f(zz[jl].z), og = sigm_f(zz[jl].w);
                float c = fg*cst[jl] + ig*gg;  cst[jl] = c;
                float h = og * tanh_f(c);
                hv[jl] = (_Float16)h;  ho[jl] = h;
            }
            if (k < SEQ) store_h8(h1ring + ((size_t)t1*BATCH + lane)*HID + wg*4, hv);
            if (t1 < SEQ-1) *reinterpret_cast<f32x4*>(out + ((size_t)t1*BATCH + lane)*HID + wg*4) = ho;
            else            ho_keep = ho;  // defer: h0ring may alias d_out upper half
            drain_vmem();
        }

        __syncthreads();   // #3: all stores drained -> flag release safe
        if (tid == 0)
            __hip_atomic_store(&flags[wg*32], k + 1, __ATOMIC_RELAXED, __HIP_MEMORY_SCOPE_AGENT);
    }

    // epilogue: all wgs past round 512's reads, then store out[511]
    if (wv == 3){
        if (wg == 0) aggregate_publish(flags, SEQ + 1, lane);
        else         wait_epoch_g(flags, SEQ + 1, rep);
        lds_publish(lds_epoch, SEQ + 1);
    }
    if (wv == 1){
        lds_wait(lds_epoch, SEQ + 1);
        *reinterpret_cast<f32x4*>(out + ((size_t)(SEQ-1)*BATCH + lane)*HID + wg*4) = ho_keep;
    }
}

// ---------------- host launcher ----------------

extern "C" void kernel_launch(void* const* d_in, const int* in_sizes, int n_in,
                              void* d_out, int out_size, void* d_ws, size_t ws_size,
                              hipStream_t stream){
    const float* x   = (const float*)d_in[0];
    const float* Wx0 = (const float*)d_in[1];
    const float* bx0 = (const float*)d_in[2];
    const float* Wh0 = (const float*)d_in[3];
    const float* bh0 = (const float*)d_in[4];
    const float* Wx1 = (const float*)d_in[5];
    const float* bx1 = (const float*)d_in[6];
    const float* Wh1 = (const float*)d_in[7];
    const float* bh1 = (const float*)d_in[8];
    float* out = (float*)d_out;
    char* ws = (char*)d_ws;

    size_t o = 0;
    _Float16* Wr0 = (_Float16*)(ws + o); o += (size_t)NG*KCAT*2;          // 16 MB
    _Float16* Wr1 = (_Float16*)(ws + o); o += (size_t)NG*KCAT*2;          // 16 MB
    float* br0 = (float*)(ws + o); o += 16384;
    float* br1 = (float*)(ws + o); o += 16384;
    _Float16* h1ring = (_Float16*)(ws + o); o += (size_t)SEQ*BATCH*HID*2; // 64 MB
    _Float16* hz     = (_Float16*)(ws + o); o += (size_t)BATCH*HID*2;     // 128 KB
    int* flags = (int*)(ws + o); o += 65536;

    const size_t RING = (size_t)SEQ*BATCH*HID*2;                          // 64 MB
    _Float16 *xbf = nullptr, *h0ring;
    int use_xf16 = 0;
    if (ws_size >= o + 2*RING){
        xbf    = (_Float16*)(ws + o);  o += RING;  use_xf16 = 1;
        h0ring = (_Float16*)(ws + o);  o += RING;
    } else if (ws_size >= o + RING){
        xbf    = (_Float16*)(ws + o);  o += RING;  use_xf16 = 1;
        h0ring = (_Float16*)((char*)d_out + (size_t)64*1024*1024);
    } else {
        h0ring = (_Float16*)((char*)d_out + (size_t)64*1024*1024);
    }
    // h0ring<->d_out-upper alias safety: proven in R5/R6 (epoch-ordered;
    // only out[511] collides -> deferred past epoch 513).

    hipFuncSetAttribute((const void*)lstm_persist,
                        hipFuncAttributeMaxDynamicSharedMemorySize, SMEM_BYTES);

    prep_w_kernel<<<NG, 256, 0, stream>>>(Wx0, Wh0, bx0, bh0, Wr0, br0);
    prep_w_kernel<<<NG, 256, 0, stream>>>(Wx1, Wh1, bx1, bh1, Wr1, br1);
    if (use_xf16)
        prep_x_kernel<<<(SEQ*BATCH*HID)/(256*8), 256, 0, stream>>>(x, xbf);
    init_misc_kernel<<<64, 256, 0, stream>>>(flags, hz);
    lstm_persist<<<256, 256, SMEM_BYTES, stream>>>(Wr0, Wr1, br0, br1, xbf, x, use_xf16,
                                                   hz, h0ring, h1ring, out, flags);
}

// Round 9
// 8842.680 us; speedup vs baseline: 2.3082x; 1.0708x over previous
//
#include <hip/hip_runtime.h>

// LSTM 2-layer, S=512 B=64 IN=H=1024, fp32 I/O, fp16 MFMA compute.
// R9: two-phase round with split flag/epoch chains.
//   Phase1 (critical cycle): x-GEMM (wv0/1) || L0h-GEMM (wv2/3, epoch0-gated)
//     -> SYNC_A -> wv0: elementwise0 -> h0 store -> flag0=k+1 (mid-round!).
//   Phase2 (overlapped): L1h0-GEMM (wv0/1) + L1h1-GEMM (wv2/3, epoch1>=k-1,
//     normally already set) -> SYNC_B -> wv1: elementwise1 -> h1/out -> flag1=k.
//   All recurrent GEMMs use explicit 2-deep A-block prefetch (16 loads in
//   flight, static-indexed buffers).
// Alias safety (h0ring in d_out upper half): phase2 reads of h0[t] complete
// before out[257+t/2] writes via the epoch1 chain; out[511] deferred past the
// final epoch0=SEQ+1 barrier.

#define SEQ   512
#define BATCH 64
#define HID   1024
#define NG    4096
#define KCAT  2048
#define F0_BASE 0            // flags0: wg*32
#define E0_IDX  8192         // epoch0 replicas: +rep*32
#define F1_BASE 16384        // flags1: wg*32
#define E1_IDX  24576        // epoch1 replicas: +rep*32

// dynamic LDS layout (bytes):
//   [0,32768)       Wh0: layer0 h-cols, 16 rows x 2048B, swizzled
//   [32768,98304)   W1 : layer1 all cols, 16 rows x 4096B, swizzled
//   [98304,133120)  accL: float[2][4][64][17]
//   [133120,133124) lds_epoch0
#define SMEM_BYTES 133504

typedef __attribute__((ext_vector_type(8))) _Float16 f16x8;
typedef __attribute__((ext_vector_type(4))) _Float16 f16x4;
typedef __attribute__((ext_vector_type(4))) float    f32x4;

__device__ __forceinline__ float sigm_f(float x){ return 1.f/(1.f + __expf(-x)); }
__device__ __forceinline__ float tanh_f(float x){
    float e = __expf(-2.f*fabsf(x));
    float r = (1.f - e)/(1.f + e);
    return copysignf(r, x);
}

__device__ __forceinline__ void store_h8(_Float16* p, f16x4 v){
    asm volatile("global_store_dwordx2 %0, %1, off sc0 sc1" :: "v"(p), "v"(v) : "memory");
}
__device__ __forceinline__ void drain_vmem(){
    asm volatile("s_waitcnt vmcnt(0)" ::: "memory");
}

// ---------------- prep kernels ----------------

__global__ void prep_w_kernel(const float* __restrict__ Wx, const float* __restrict__ Wh,
                              const float* __restrict__ bx, const float* __restrict__ bh,
                              _Float16* __restrict__ Wr, float* __restrict__ br){
    int p = blockIdx.x;
    int j = p >> 2, g = p & 3;
    int r = g*1024 + j;
    int k = threadIdx.x * 8;
    const float* s = (k < 1024) ? (Wx + (size_t)r*1024 + k)
                                : (Wh + (size_t)r*1024 + (k - 1024));
    float4 v0 = *reinterpret_cast<const float4*>(s);
    float4 v1 = *reinterpret_cast<const float4*>(s + 4);
    f16x8 o;
    o[0]=(_Float16)v0.x; o[1]=(_Float16)v0.y; o[2]=(_Float16)v0.z; o[3]=(_Float16)v0.w;
    o[4]=(_Float16)v1.x; o[5]=(_Float16)v1.y; o[6]=(_Float16)v1.z; o[7]=(_Float16)v1.w;
    *reinterpret_cast<f16x8*>(Wr + (size_t)p*KCAT + k) = o;
    if (threadIdx.x == 0) br[p] = bx[r] + bh[r];
}

__global__ void prep_x_kernel(const float* __restrict__ x, _Float16* xo){
    size_t i = ((size_t)blockIdx.x*256 + threadIdx.x) * 8;
    float4 v0 = *reinterpret_cast<const float4*>(x + i);
    float4 v1 = *reinterpret_cast<const float4*>(x + i + 4);
    f16x8 o;
    o[0]=(_Float16)v0.x; o[1]=(_Float16)v0.y; o[2]=(_Float16)v0.z; o[3]=(_Float16)v0.w;
    o[4]=(_Float16)v1.x; o[5]=(_Float16)v1.y; o[6]=(_Float16)v1.z; o[7]=(_Float16)v1.w;
    *reinterpret_cast<f16x8*>(xo + i) = o;
}

__global__ void init_misc_kernel(int* flags, _Float16* hz){
    int i = blockIdx.x*256 + threadIdx.x;            // 32768 threads
    flags[i] = 0;
    if (i < 16384){
        f16x4 z; z[0]=(_Float16)0.f; z[1]=(_Float16)0.f; z[2]=(_Float16)0.f; z[3]=(_Float16)0.f;
        *reinterpret_cast<f16x4*>(hz + (size_t)i*4) = z;
    }
}

// ---------------- sync helpers (no fences) ----------------

__device__ __forceinline__ void wait_epoch_g(const int* flags, int eidx, int k, int rep){
    for(;;){
        int e = __hip_atomic_load(&flags[eidx + rep*32], __ATOMIC_RELAXED, __HIP_MEMORY_SCOPE_AGENT);
        if (e >= k) break;
        __builtin_amdgcn_s_sleep(2);
    }
    asm volatile("" ::: "memory");
}

// poll all 256 per-wg flags at base, then publish epoch k to 8 replicas
__device__ __forceinline__ void aggregate_publish(int* flags, int base, int eidx,
                                                  int k, int lane){
    const int b = lane*4;
    for(;;){
        int a0 = __hip_atomic_load(&flags[base + (b+0)*32], __ATOMIC_RELAXED, __HIP_MEMORY_SCOPE_AGENT);
        int a1 = __hip_atomic_load(&flags[base + (b+1)*32], __ATOMIC_RELAXED, __HIP_MEMORY_SCOPE_AGENT);
        int a2 = __hip_atomic_load(&flags[base + (b+2)*32], __ATOMIC_RELAXED, __HIP_MEMORY_SCOPE_AGENT);
        int a3 = __hip_atomic_load(&flags[base + (b+3)*32], __ATOMIC_RELAXED, __HIP_MEMORY_SCOPE_AGENT);
        bool ok = (a0>=k) && (a1>=k) && (a2>=k) && (a3>=k);
        if (__all(ok)) break;
        __builtin_amdgcn_s_sleep(1);
    }
    asm volatile("" ::: "memory");
    if (lane < 8)
        __hip_atomic_store(&flags[eidx + lane*32], k, __ATOMIC_RELAXED, __HIP_MEMORY_SCOPE_AGENT);
}

__device__ __forceinline__ void lds_publish(int* e, int k){
    __hip_atomic_store(e, k, __ATOMIC_RELAXED, __HIP_MEMORY_SCOPE_WORKGROUP);
}
__device__ __forceinline__ void lds_wait(int* e, int k){
    while (__hip_atomic_load(e, __ATOMIC_RELAXED, __HIP_MEMORY_SCOPE_WORKGROUP) < k)
        __builtin_amdgcn_s_sleep(1);
    asm volatile("" ::: "memory");
}

// ---------------- GEMM helpers ----------------

__device__ __forceinline__ f32x4 mfma16(f16x8 a, f16x8 b, f32x4 c){
    return __builtin_amdgcn_mfma_f32_16x16x32_f16(a, b, c, 0, 0, 0);
}

// pipelined GEMM, B from LDS: 2-deep A-block prefetch (block = 4 kk = 16 loads)
__device__ __forceinline__ void gemm_pipe_ldsb(const _Float16* A, const char* wrow,
                                               int c0, int swz, f32x4* acc){
    f16x8 abuf[2][16];
    #pragma unroll
    for (int kk = 0; kk < 4; ++kk)
        #pragma unroll
        for (int m = 0; m < 4; ++m)
            abuf[0][kk*4+m] = *reinterpret_cast<const f16x8*>(A + kk*32 + m*16*1024);
    #pragma unroll
    for (int b = 0; b < 4; ++b){
        if (b < 3){
            #pragma unroll
            for (int kk = 0; kk < 4; ++kk)
                #pragma unroll
                for (int m = 0; m < 4; ++m)
                    abuf[(b+1)&1][kk*4+m] =
                        *reinterpret_cast<const f16x8*>(A + (b+1)*128 + kk*32 + m*16*1024);
        }
        #pragma unroll
        for (int kk = 0; kk < 4; ++kk){
            const int kg = b*4 + kk;
            f16x8 bb = *reinterpret_cast<const f16x8*>(wrow + ((c0 + kg*64) ^ swz));
            acc[0] = mfma16(abuf[b&1][kk*4+0], bb, acc[0]);
            acc[1] = mfma16(abuf[b&1][kk*4+1], bb, acc[1]);
            acc[2] = mfma16(abuf[b&1][kk*4+2], bb, acc[2]);
            acc[3] = mfma16(abuf[b&1][kk*4+3], bb, acc[3]);
        }
    }
}

// pipelined GEMM, B from global (x-weights, L2-resident)
__device__ __forceinline__ void gemm_pipe_gb(const _Float16* A, const _Float16* Wp,
                                             f32x4* acc){
    f16x8 abuf[2][16];
    #pragma unroll
    for (int kk = 0; kk < 4; ++kk)
        #pragma unroll
        for (int m = 0; m < 4; ++m)
            abuf[0][kk*4+m] = *reinterpret_cast<const f16x8*>(A + kk*32 + m*16*1024);
    #pragma unroll
    for (int b = 0; b < 4; ++b){
        if (b < 3){
            #pragma unroll
            for (int kk = 0; kk < 4; ++kk)
                #pragma unroll
                for (int m = 0; m < 4; ++m)
                    abuf[(b+1)&1][kk*4+m] =
                        *reinterpret_cast<const f16x8*>(A + (b+1)*128 + kk*32 + m*16*1024);
        }
        #pragma unroll
        for (int kk = 0; kk < 4; ++kk){
            const int kg = b*4 + kk;
            f16x8 bb = *reinterpret_cast<const f16x8*>(Wp + kg*32);
            acc[0] = mfma16(abuf[b&1][kk*4+0], bb, acc[0]);
            acc[1] = mfma16(abuf[b&1][kk*4+1], bb, acc[1]);
            acc[2] = mfma16(abuf[b&1][kk*4+2], bb, acc[2]);
            acc[3] = mfma16(abuf[b&1][kk*4+3], bb, acc[3]);
        }
    }
}

__device__ __forceinline__ void gemm_q_f32(const float* A, const _Float16* Wp, f32x4* acc){
    #pragma unroll 2
    for (int kk = 0; kk < 16; ++kk){
        f16x8 b = *reinterpret_cast<const f16x8*>(Wp + kk*32);
        f16x8 a[4];
        #pragma unroll
        for (int m = 0; m < 4; ++m){
            float4 u0 = *reinterpret_cast<const float4*>(A + kk*32 + (size_t)m*16*1024);
            float4 u1 = *reinterpret_cast<const float4*>(A + kk*32 + (size_t)m*16*1024 + 4);
            f16x8 v;
            v[0]=(_Float16)u0.x; v[1]=(_Float16)u0.y; v[2]=(_Float16)u0.z; v[3]=(_Float16)u0.w;
            v[4]=(_Float16)u1.x; v[5]=(_Float16)u1.y; v[6]=(_Float16)u1.z; v[7]=(_Float16)u1.w;
            a[m] = v;
        }
        acc[0] = mfma16(a[0], b, acc[0]);
        acc[1] = mfma16(a[1], b, acc[1]);
        acc[2] = mfma16(a[2], b, acc[2]);
        acc[3] = mfma16(a[3], b, acc[3]);
    }
}

// ---------------- persistent LSTM kernel ----------------

__global__ __launch_bounds__(256, 1)
void lstm_persist(const _Float16* __restrict__ Wr0, const _Float16* __restrict__ Wr1,
                  const float* __restrict__ br0, const float* __restrict__ br1,
                  const _Float16* __restrict__ xbf, const float* __restrict__ xf32,
                  int use_xf16, const _Float16* __restrict__ hz,
                  _Float16* h0ring, _Float16* h1ring, float* out, int* flags){
    extern __shared__ char smem[];
    float (*accL)[4][64][17] = reinterpret_cast<float(*)[4][64][17]>(smem + 98304);
    int* ldsE = reinterpret_cast<int*>(smem + 133120);

    const int tid  = threadIdx.x;
    const int wg   = blockIdx.x;
    const int wv   = tid >> 6;
    const int lane = tid & 63;
    const int r    = lane & 15;
    const int q    = lane >> 4;
    const int p0   = wg * 16;
    const int rep  = wg & 7;
    const int swz  = (r & 7) << 4;

    // stage recurrent-path weights into LDS (once)
    for (int idx = tid; idx < 6144; idx += 256){
        int rr, cb; char* dst; const _Float16* s;
        if (idx < 2048){
            rr = idx >> 7;  cb = (idx & 127) << 4;
            s   = Wr0 + (size_t)(p0 + rr)*KCAT + 1024 + (cb >> 1);
            dst = smem + rr*2048 + (cb ^ ((rr & 7) << 4));
        } else {
            int j2 = idx - 2048;
            rr = j2 >> 8;  cb = (j2 & 255) << 4;
            s   = Wr1 + (size_t)(p0 + rr)*KCAT + (cb >> 1);
            dst = smem + 32768 + rr*4096 + (cb ^ ((rr & 7) << 4));
        }
        *reinterpret_cast<f16x8*>(dst) = *reinterpret_cast<const f16x8*>(s);
    }
    if (tid == 0) *ldsE = 0;
    __syncthreads();

    f32x4 cst = {0.f,0.f,0.f,0.f};
    f32x4 ho_keep = {0.f,0.f,0.f,0.f};
    f32x4 bias[4];
    {
        const float* bsrc = (wv == 0) ? br0 : br1;
        #pragma unroll
        for (int jj = 0; jj < 4; ++jj)
            bias[jj] = *reinterpret_cast<const f32x4*>(&bsrc[p0 + jj*4]);
    }

    const int kofs = (wv & 1)*512 + q*8;
    const int wcol = wv*512 + q*8;
    const char* w1row  = smem + 32768 + r*4096;
    const char* wh0row = smem + r*2048;
    const size_t BH = (size_t)BATCH*HID;

    for (int k = 0; k <= SEQ; ++k){
        // ================= PHASE 1 =================
        f32x4 acc[4];
        #pragma unroll
        for (int m = 0; m < 4; ++m){ acc[m].x=0;acc[m].y=0;acc[m].z=0;acc[m].w=0; }

        if (wv < 2){
            if (k < SEQ){
                if (use_xf16)
                    gemm_pipe_gb(xbf + (size_t)k*BH + (size_t)r*HID + kofs,
                                 Wr0 + (size_t)(p0 + r)*KCAT + wcol, acc);
                else
                    gemm_q_f32(xf32 + (size_t)k*BH + (size_t)r*HID + kofs,
                               Wr0 + (size_t)(p0 + r)*KCAT + wcol, acc);
            }
        } else {
            if (k > 0){
                if (wv == 3){
                    if (wg == 0) aggregate_publish(flags, F0_BASE, E0_IDX, k, lane);
                    else         wait_epoch_g(flags, E0_IDX, k, rep);
                    lds_publish(ldsE, k);
                } else {
                    lds_wait(ldsE, k);
                }
            }
            if (k < SEQ){
                const _Float16* A0 = (k == 0) ? (hz + (size_t)r*HID + kofs)
                                              : (h0ring + (size_t)(k-1)*BH + (size_t)r*HID + kofs);
                gemm_pipe_ldsb(A0, wh0row, (wv-2)*1024 + q*16, swz, acc);
            }
        }

        #pragma unroll
        for (int mt = 0; mt < 4; ++mt)
            #pragma unroll
            for (int j = 0; j < 4; ++j)
                accL[0][wv][mt*16 + q*4 + j][r] = acc[mt][j];
        __syncthreads();   // SYNC_A

        if (wv == 0 && k < SEQ){
            f32x4 zz[4];
            #pragma unroll
            for (int jj = 0; jj < 4; ++jj) zz[jj] = bias[jj];
            #pragma unroll
            for (int w2 = 0; w2 < 4; ++w2)
                #pragma unroll
                for (int jj = 0; jj < 4; ++jj){
                    f32x4 a = *reinterpret_cast<const f32x4*>(&accL[0][w2][lane][jj*4]);
                    zz[jj].x += a.x; zz[jj].y += a.y; zz[jj].z += a.z; zz[jj].w += a.w;
                }
            f16x4 hv;
            #pragma unroll
            for (int jl = 0; jl < 4; ++jl){
                float ig = sigm_f(zz[jl].x), fg = sigm_f(zz[jl].y);
                float gg = tanh_f(zz[jl].z), og = sigm_f(zz[jl].w);
                float c = fg*cst[jl] + ig*gg;  cst[jl] = c;
                hv[jl] = (_Float16)(og * tanh_f(c));
            }
            store_h8(h0ring + ((size_t)k*BATCH + lane)*HID + wg*4, hv);
            drain_vmem();
            if (lane == 0)
                __hip_atomic_store(&flags[F0_BASE + wg*32], k + 1,
                                   __ATOMIC_RELAXED, __HIP_MEMORY_SCOPE_AGENT);
        }

        // ================= PHASE 2 =================
        #pragma unroll
        for (int m = 0; m < 4; ++m){ acc[m].x=0;acc[m].y=0;acc[m].z=0;acc[m].w=0; }

        if (k >= 1){
            if (wv < 2){
                gemm_pipe_ldsb(h0ring + (size_t)(k-1)*BH + (size_t)r*HID + kofs,
                               w1row, wv*1024 + q*16, swz, acc);
            } else {
                if (k >= 2){
                    if (wg == 0 && wv == 2) aggregate_publish(flags, F1_BASE, E1_IDX, k-1, lane);
                    else                    wait_epoch_g(flags, E1_IDX, k-1, rep);
                }
                const _Float16* A1 = (k == 1) ? (hz + (size_t)r*HID + kofs)
                                              : (h1ring + (size_t)(k-2)*BH + (size_t)r*HID + kofs);
                gemm_pipe_ldsb(A1, w1row, wv*1024 + q*16, swz, acc);
            }
        }

        #pragma unroll
        for (int mt = 0; mt < 4; ++mt)
            #pragma unroll
            for (int j = 0; j < 4; ++j)
                accL[1][wv][mt*16 + q*4 + j][r] = acc[mt][j];
        __syncthreads();   // SYNC_B

        if (wv == 1 && k >= 1){
            const int t1 = k - 1;
            f32x4 zz[4];
            #pragma unroll
            for (int jj = 0; jj < 4; ++jj) zz[jj] = bias[jj];
            #pragma unroll
            for (int w2 = 0; w2 < 4; ++w2)
                #pragma unroll
                for (int jj = 0; jj < 4; ++jj){
                    f32x4 a = *reinterpret_cast<const f32x4*>(&accL[1][w2][lane][jj*4]);
                    zz[jj].x += a.x; zz[jj].y += a.y; zz[jj].z += a.z; zz[jj].w += a.w;
                }
            f16x4 hv; f32x4 ho;
            #pragma unroll
            for (int jl = 0; jl < 4; ++jl){
                float ig = sigm_f(zz[jl].x), fg = sigm_f(zz[jl].y);
                float gg = tanh_f(zz[jl].z), og = sigm_f(zz[jl].w);
                float c = fg*cst[jl] + ig*gg;  cst[jl] = c;
                float h = og * tanh_f(c);
                hv[jl] = (_Float16)h;  ho[jl] = h;
            }
            if (k < SEQ) store_h8(h1ring + ((size_t)t1*BATCH + lane)*HID + wg*4, hv);
            if (t1 < SEQ-1) *reinterpret_cast<f32x4*>(out + ((size_t)t1*BATCH + lane)*HID + wg*4) = ho;
            else            ho_keep = ho;   // out[511] deferred (alias safety)
            drain_vmem();
            if (lane == 0)
                __hip_atomic_store(&flags[F1_BASE + wg*32], k,
                                   __ATOMIC_RELAXED, __HIP_MEMORY_SCOPE_AGENT);
        }
    }

    // epilogue: flag0=SEQ+1 after all local reads of h0[511]; then out[511]
    if (tid == 0)
        __hip_atomic_store(&flags[F0_BASE + wg*32], SEQ + 1,
                           __ATOMIC_RELAXED, __HIP_MEMORY_SCOPE_AGENT);
    if (wg == 0 && wv == 3) aggregate_publish(flags, F0_BASE, E0_IDX, SEQ + 1, lane);
    if (wv == 1){
        wait_epoch_g(flags, E0_IDX, SEQ + 1, rep);
        *reinterpret_cast<f32x4*>(out + ((size_t)(SEQ-1)*BATCH + lane)*HID + wg*4) = ho_keep;
    }
}

// ---------------- host launcher ----------------

extern "C" void kernel_launch(void* const* d_in, const int* in_sizes, int n_in,
                              void* d_out, int out_size, void* d_ws, size_t ws_size,
                              hipStream_t stream){
    const float* x   = (const float*)d_in[0];
    const float* Wx0 = (const float*)d_in[1];
    const float* bx0 = (const float*)d_in[2];
    const float* Wh0 = (const float*)d_in[3];
    const float* bh0 = (const float*)d_in[4];
    const float* Wx1 = (const float*)d_in[5];
    const float* bx1 = (const float*)d_in[6];
    const float* Wh1 = (const float*)d_in[7];
    const float* bh1 = (const float*)d_in[8];
    float* out = (float*)d_out;
    char* ws = (char*)d_ws;

    size_t o = 0;
    _Float16* Wr0 = (_Float16*)(ws + o); o += (size_t)NG*KCAT*2;
    _Float16* Wr1 = (_Float16*)(ws + o); o += (size_t)NG*KCAT*2;
    float* br0 = (float*)(ws + o); o += 16384;
    float* br1 = (float*)(ws + o); o += 16384;
    _Float16* h1ring = (_Float16*)(ws + o); o += (size_t)SEQ*BATCH*HID*2;
    _Float16* hz     = (_Float16*)(ws + o); o += (size_t)BATCH*HID*2;
    int* flags = (int*)(ws + o); o += 131072;     // flags0/1 + epoch0/1 replicas

    const size_t RING = (size_t)SEQ*BATCH*HID*2;
    _Float16 *xbf = nullptr, *h0ring;
    int use_xf16 = 0;
    if (ws_size >= o + 2*RING){
        xbf    = (_Float16*)(ws + o);  o += RING;  use_xf16 = 1;
        h0ring = (_Float16*)(ws + o);  o += RING;
    } else if (ws_size >= o + RING){
        xbf    = (_Float16*)(ws + o);  o += RING;  use_xf16 = 1;
        h0ring = (_Float16*)((char*)d_out + (size_t)64*1024*1024);
    } else {
        h0ring = (_Float16*)((char*)d_out + (size_t)64*1024*1024);
    }

    hipFuncSetAttribute((const void*)lstm_persist,
                        hipFuncAttributeMaxDynamicSharedMemorySize, SMEM_BYTES);

    prep_w_kernel<<<NG, 256, 0, stream>>>(Wx0, Wh0, bx0, bh0, Wr0, br0);
    prep_w_kernel<<<NG, 256, 0, stream>>>(Wx1, Wh1, bx1, bh1, Wr1, br1);
    if (use_xf16)
        prep_x_kernel<<<(SEQ*BATCH*HID)/(256*8), 256, 0, stream>>>(x, xbf);
    init_misc_kernel<<<128, 256, 0, stream>>>(flags, hz);
    lstm_persist<<<256, 256, SMEM_BYTES, stream>>>(Wr0, Wr1, br0, br1, xbf, x, use_xf16,
                                                   hz, h0ring, h1ring, out, flags);
}